// Round 1
// 599.779 us; speedup vs baseline: 1.0819x; 1.0819x over previous
//
#include <hip/hip_runtime.h>

typedef __bf16 bf16x8 __attribute__((ext_vector_type(8)));
typedef float f32x4 __attribute__((ext_vector_type(4)));

#define SCLOG 0.04508422f   // (1024^-0.5) * log2(e)

// ---------- helpers ----------
__device__ __forceinline__ unsigned short f2bf(float f) {
  union { float f; unsigned int u; } v;
  v.f = f;
  unsigned int u = v.u;
  u += 0x7fffu + ((u >> 16) & 1u);   // RNE
  return (unsigned short)(u >> 16);
}

__device__ __forceinline__ unsigned asuint(float f) {
  union { float f; unsigned u; } v; v.f = f; return v.u;
}

__device__ __forceinline__ void gld_lds16(const void* g, void* l) {
  __builtin_amdgcn_global_load_lds(
      (const __attribute__((address_space(1))) void*)g,
      (__attribute__((address_space(3))) void*)l, 16, 0, 0);
}

// ---------- kernel 1: fp32 -> bf16 conversion ----------
__global__ __launch_bounds__(256) void convert_kernel(
    const float* __restrict__ q, const float* __restrict__ k,
    const float* __restrict__ wq, const float* __restrict__ wk,
    const float* __restrict__ wv, const float* __restrict__ wp,
    unsigned short* __restrict__ qb, unsigned short* __restrict__ kb,
    unsigned short* __restrict__ Wqkv, unsigned short* __restrict__ Wpb) {
  size_t i = (size_t)blockIdx.x * 256 + threadIdx.x;
  const float* src; unsigned short* dst; size_t off;
  if (i < 4194304)      { src = q;  dst = qb;             off = i; }
  else if (i < 8388608) { src = k;  dst = kb;             off = i - 4194304; }
  else if (i < 8650752) { src = wq; dst = Wqkv;           off = i - 8388608; }
  else if (i < 8912896) { src = wk; dst = Wqkv + 1048576; off = i - 8650752; }
  else if (i < 9175040) { src = wv; dst = Wqkv + 2097152; off = i - 8912896; }
  else                  { src = wp; dst = Wpb;            off = i - 9175040; }
  float4 v = ((const float4*)src)[off];
  ushort4 o;
  o.x = f2bf(v.x); o.y = f2bf(v.y); o.z = f2bf(v.z); o.w = f2bf(v.w);
  ((ushort4*)dst)[off] = o;
}

// ---------- kernel 2: fused QKV GEMM (round-1 proven) ----------
__global__ __launch_bounds__(256) void gemm_qkv_kernel(
    const unsigned short* __restrict__ qb,
    const unsigned short* __restrict__ kb,
    const unsigned short* __restrict__ W,       // [3072][1024]
    unsigned short* __restrict__ Qo,
    unsigned short* __restrict__ Ko,
    unsigned short* __restrict__ Vo) {
  __shared__ unsigned short Alds[128 * 32];
  __shared__ unsigned short Blds[128 * 32];
  const int t   = threadIdx.x;
  const int bid = blockIdx.x;
  const int tn  = bid % 24;
  const int tm  = bid / 24;
  const unsigned short* Aptr = (tn < 8) ? qb : kb;
  const unsigned short* Bptr = W + (size_t)tn * 128 * 1024;

  const int lane = t & 63;
  const int wv   = t >> 6;
  const int wm   = (wv >> 1) * 64;
  const int wn   = (wv & 1) * 64;
  const int fr   = lane & 15;
  const int kq   = (lane >> 4) * 8;

  f32x4 acc[4][4];
#pragma unroll
  for (int i = 0; i < 4; i++)
#pragma unroll
    for (int j = 0; j < 4; j++) acc[i][j] = (f32x4){0.f, 0.f, 0.f, 0.f};

  const int sr = t >> 2;
  const int sc = (t & 3) << 3;
  const unsigned short* gA = Aptr + (size_t)(tm * 128 + sr) * 1024 + sc;
  const unsigned short* gB = Bptr + (size_t)sr * 1024 + sc;
  unsigned short* lA = Alds + t * 8;
  unsigned short* lB = Blds + t * 8;

  for (int k0 = 0; k0 < 1024; k0 += 32) {
    gld_lds16(gA, lA);
    gld_lds16(gA + 64 * 1024, lA + 64 * 32);
    gld_lds16(gB, lB);
    gld_lds16(gB + 64 * 1024, lB + 64 * 32);
    gA += 32; gB += 32;
    __syncthreads();
    bf16x8 af[4], bfr[4];
#pragma unroll
    for (int i = 0; i < 4; i++) {
      af[i]  = *(const bf16x8*)&Alds[(wm + i * 16 + fr) * 32 + kq];
      bfr[i] = *(const bf16x8*)&Blds[(wn + i * 16 + fr) * 32 + kq];
    }
#pragma unroll
    for (int i = 0; i < 4; i++)
#pragma unroll
      for (int j = 0; j < 4; j++)
        acc[i][j] = __builtin_amdgcn_mfma_f32_16x16x32_bf16(af[i], bfr[j], acc[i][j], 0, 0, 0);
    __syncthreads();
  }

  const int sel = tn >> 3;  // 0=Q 1=K 2=V
  unsigned short* Out = sel == 0 ? Qo : (sel == 1 ? Ko : Vo);
  const int ncol0 = tn * 128 - sel * 1024 + wn;
  const int quad = lane >> 4;
  const int cc   = lane & 15;
#pragma unroll
  for (int i = 0; i < 4; i++)
#pragma unroll
    for (int j = 0; j < 4; j++)
#pragma unroll
      for (int r = 0; r < 4; r++) {
        int row = tm * 128 + wm + i * 16 + quad * 4 + r;
        int col = ncol0 + j * 16 + cc;
        Out[(size_t)row * 1024 + col] = f2bf(acc[i][j][r]);
      }
}

// ---------- kernel 3: per-group V transpose (round-1 proven) ----------
__global__ __launch_bounds__(256) void vtrans_kernel(
    const unsigned short* __restrict__ V, unsigned short* __restrict__ Vt) {
  __shared__ unsigned short T[128 * 136];
  const int g  = blockIdx.x >> 4;
  const int kt = blockIdx.x & 15;
  const unsigned short* Vg = V + (size_t)g * 262144 + (size_t)kt * 128 * 128;
  unsigned short* Vtg = Vt + (size_t)g * 262144 + kt * 128;
  const int t = threadIdx.x;
#pragma unroll
  for (int it = 0; it < 8; it++) {
    int seg = t + it * 256;
    int k  = seg >> 4;
    int c8 = (seg & 15) << 3;
    uint4 a = *(const uint4*)(Vg + k * 128 + c8);
    unsigned short* Tp = &T[c8 * 136 + k];
    Tp[0 * 136] = (unsigned short)(a.x & 0xffff);
    Tp[1 * 136] = (unsigned short)(a.x >> 16);
    Tp[2 * 136] = (unsigned short)(a.y & 0xffff);
    Tp[3 * 136] = (unsigned short)(a.y >> 16);
    Tp[4 * 136] = (unsigned short)(a.z & 0xffff);
    Tp[5 * 136] = (unsigned short)(a.z >> 16);
    Tp[6 * 136] = (unsigned short)(a.w & 0xffff);
    Tp[7 * 136] = (unsigned short)(a.w >> 16);
  }
  __syncthreads();
#pragma unroll
  for (int it = 0; it < 8; it++) {
    int seg = t + it * 256;
    int c  = seg >> 4;
    int k8 = (seg & 15) << 3;
    uint4 o = *(const uint4*)&T[c * 136 + k8];
    *(uint4*)(Vtg + (size_t)c * 2048 + k8) = o;
  }
}

// ---------- kernel 4: flash attention, S^T orientation, swizzled LDS ----------
// grid: 64 groups x 16 q-tiles of 128 rows; 32 KV tiles of 64 keys.
// v2: double-buffered K/V staging, prefetch tile kt+1 before computing kt,
//     ONE barrier per tile (T3 minimum-2-phase). LDS 80KB -> 2 blocks/CU.
__global__ __launch_bounds__(256, 2) void attn_kernel(
    const unsigned short* __restrict__ Q,
    const unsigned short* __restrict__ K,
    const unsigned short* __restrict__ Vt,   // bf16 [64][128 chunk][2048 key]
    unsigned short* __restrict__ ctx) {
  // layout (80 KB total, 2 blocks/CU = 160 KiB exactly):
  //   Kbuf[b] = smem +     b*16384   [64 key][256B], chunk c at p=(c&8)|((c^r)&7)
  //   Vbuf[b] = smem + 32768 + b*16384 [128 chunk][128B], chunk c at p=c^(r&7)
  //   Psh     = smem + 65536         [128 qrow][128B], chunk c at p=c^(r&7)
  //   linv    overlaid on Psh after the loop (Psh dead then)
  __shared__ unsigned char smem[81920];
  unsigned char* Psh = smem + 65536;

  const int g  = blockIdx.x >> 4;
  const int qt = blockIdx.x & 15;
  const unsigned short* Qg = Q + (size_t)g * 262144 + (size_t)qt * 16384;
  const unsigned short* Kg = K + (size_t)g * 262144;
  const unsigned short* Vg = Vt + (size_t)g * 262144;   // [128][2048]

  const int t    = threadIdx.x;
  const int lane = t & 63;
  const int wv   = t >> 6;
  const int fr   = lane & 15;
  const int quad = lane >> 4;

  // stage Q [128 rows x 256B] swizzled into smem[0..32768)
#pragma unroll
  for (int it = 0; it < 8; it++) {
    int seg = t + it * 256;
    int r = seg >> 4, p = seg & 15;
    int c = (p & 8) | ((p ^ r) & 7);
    gld_lds16(Qg + r * 128 + c * 8, smem + seg * 16);
  }
  __syncthreads();
  bf16x8 qf[2][4];   // B-frag: Q[qrow = wv*32+nt*16+fr][k = kc*32+quad*8+j]
#pragma unroll
  for (int nt = 0; nt < 2; nt++)
#pragma unroll
    for (int kc = 0; kc < 4; kc++) {
      int row = wv * 32 + nt * 16 + fr;
      int c = kc * 4 + quad;
      int p = (c & 8) | ((c ^ (row & 7)) & 7);
      qf[nt][kc] = *(const bf16x8*)(smem + row * 256 + p * 16);
    }
  __syncthreads();   // all waves done reading Q region (Kbufs overlay it)

  // prologue: stage tile 0 into buffer 0
#pragma unroll
  for (int it = 0; it < 4; it++) {
    int seg = t + it * 256;
    int r = seg >> 4, p = seg & 15;
    int c = (p & 8) | ((p ^ r) & 7);
    gld_lds16(Kg + (size_t)r * 128 + c * 8, smem + seg * 16);
  }
#pragma unroll
  for (int it = 0; it < 4; it++) {
    int seg = t + it * 256;
    int r = seg >> 3, p = seg & 7;
    int c = p ^ (r & 7);
    gld_lds16(Vg + (size_t)r * 2048 + c * 8, smem + 32768 + seg * 16);
  }
  __syncthreads();   // drains vmcnt(0): tile 0 resident

  f32x4 O[2][8];   // D[qrow][chunk]
#pragma unroll
  for (int qb2 = 0; qb2 < 2; qb2++)
#pragma unroll
    for (int cb = 0; cb < 8; cb++) O[qb2][cb] = (f32x4){0.f, 0.f, 0.f, 0.f};
  float lp[2] = {0.f, 0.f};

#pragma unroll 1
  for (int kt = 0; kt < 32; kt++) {
    unsigned char* Ksh = smem + (unsigned)(kt & 1) * 16384;
    unsigned char* Vsh = smem + 32768 + (unsigned)(kt & 1) * 16384;

    // prefetch tile kt+1 into the other buffer; latency hides under compute
    if (kt < 31) {
      unsigned char* Kst = smem + (unsigned)((kt + 1) & 1) * 16384;
      unsigned char* Vst = smem + 32768 + (unsigned)((kt + 1) & 1) * 16384;
#pragma unroll
      for (int it = 0; it < 4; it++) {
        int seg = t + it * 256;
        int r = seg >> 4, p = seg & 15;
        int c = (p & 8) | ((p ^ r) & 7);
        gld_lds16(Kg + (size_t)((kt + 1) * 64 + r) * 128 + c * 8, Kst + seg * 16);
      }
#pragma unroll
      for (int it = 0; it < 4; it++) {
        int seg = t + it * 256;
        int r = seg >> 3, p = seg & 7;
        int c = p ^ (r & 7);
        gld_lds16(Vg + (size_t)r * 2048 + (kt + 1) * 64 + c * 8, Vst + seg * 16);
      }
    }

    // S^T = K Q^T; in-lane softmax (clamped, no max-tracking); pack bf16 P
#pragma unroll
    for (int mt = 0; mt < 4; mt++) {
      bf16x8 kf[4];
#pragma unroll
      for (int kc = 0; kc < 4; kc++) {
        int row = mt * 16 + fr;
        int c = kc * 4 + quad;
        int p = (c & 8) | ((c ^ (row & 7)) & 7);
        kf[kc] = *(const bf16x8*)(Ksh + row * 256 + p * 16);
      }
#pragma unroll
      for (int nt = 0; nt < 2; nt++) {
        f32x4 s = (f32x4){0.f, 0.f, 0.f, 0.f};
#pragma unroll
        for (int kc = 0; kc < 4; kc++)
          s = __builtin_amdgcn_mfma_f32_16x16x32_bf16(kf[kc], qf[nt][kc], s, 0, 0, 0);
        // lane holds S^T[key = mt*16+quad*4+r][qrow = wv*32+nt*16+fr]
        float p0 = exp2f(fminf(s[0] * SCLOG, 30.f));
        float p1 = exp2f(fminf(s[1] * SCLOG, 30.f));
        float p2 = exp2f(fminf(s[2] * SCLOG, 30.f));
        float p3 = exp2f(fminf(s[3] * SCLOG, 30.f));
        lp[nt] += (p0 + p1) + (p2 + p3);
        // pack 4 bf16 (round-half-up) via v_perm
        unsigned u01 = __builtin_amdgcn_perm(asuint(p1) + 0x8000u, asuint(p0) + 0x8000u, 0x07060302u);
        unsigned u23 = __builtin_amdgcn_perm(asuint(p3) + 0x8000u, asuint(p2) + 0x8000u, 0x07060302u);
        int qrow = wv * 32 + nt * 16 + fr;
        int cP = mt * 2 + (quad >> 1);            // 16B-chunk of keys key0/8
        int pP = cP ^ (qrow & 7);
        uint2 u2; u2.x = u01; u2.y = u23;
        *(uint2*)(Psh + qrow * 128 + pP * 16 + (quad & 1) * 8) = u2;
      }
    }

    // O += P @ V  (P rows wave-private: no barrier needed)
    bf16x8 pf[2][2];
#pragma unroll
    for (int qb2 = 0; qb2 < 2; qb2++)
#pragma unroll
      for (int k2 = 0; k2 < 2; k2++) {
        int qrow = wv * 32 + qb2 * 16 + fr;
        int c = k2 * 4 + quad;
        int p = c ^ (qrow & 7);
        pf[qb2][k2] = *(const bf16x8*)(Psh + qrow * 128 + p * 16);
      }
#pragma unroll
    for (int cb = 0; cb < 8; cb++)
#pragma unroll
      for (int k2 = 0; k2 < 2; k2++) {
        int crow = cb * 16 + fr;
        int c = k2 * 4 + quad;
        int p = c ^ (crow & 7);
        bf16x8 vf = *(const bf16x8*)(Vsh + crow * 128 + p * 16);
#pragma unroll
        for (int qb2 = 0; qb2 < 2; qb2++)
          O[qb2][cb] = __builtin_amdgcn_mfma_f32_16x16x32_bf16(pf[qb2][k2], vf, O[qb2][cb], 0, 0, 0);
      }

    // single barrier per tile: drains prefetch (vmcnt) AND protects the
    // buffer being overwritten next iteration (read two iterations ago)
    __syncthreads();
  }

  // row-sum across quads (once per block), then normalize + write ctx
  // linv overlaid on Psh (dead after final barrier)
  float* linv_arr = (float*)(smem + 65536);
#pragma unroll
  for (int nt = 0; nt < 2; nt++) {
    float v = lp[nt];
    v += __shfl_xor(v, 16);
    v += __shfl_xor(v, 32);
    if (quad == 0) linv_arr[wv * 32 + nt * 16 + fr] = 1.f / v;
  }
  unsigned short* Cg = ctx + (size_t)g * 262144 + (size_t)qt * 16384;
#pragma unroll
  for (int qb2 = 0; qb2 < 2; qb2++) {
    float li[4];
#pragma unroll
    for (int r = 0; r < 4; r++) li[r] = linv_arr[wv * 32 + qb2 * 16 + quad * 4 + r];
#pragma unroll
    for (int cb = 0; cb < 8; cb++)
#pragma unroll
      for (int r = 0; r < 4; r++) {
        int qrow = wv * 32 + qb2 * 16 + quad * 4 + r;
        Cg[(size_t)qrow * 128 + cb * 16 + fr] = f2bf(O[qb2][cb][r] * li[r]);
      }
  }
}

// ---------- kernel 5: output projection + bias + residual ----------
__global__ __launch_bounds__(256) void gemm_proj_kernel(
    const unsigned short* __restrict__ A,
    const unsigned short* __restrict__ W,
    const float* __restrict__ bp,
    const float* __restrict__ qres,
    float* __restrict__ out) {
  __shared__ unsigned short Alds[128 * 32];
  __shared__ unsigned short Blds[128 * 32];
  const int t   = threadIdx.x;
  const int bid = blockIdx.x;
  const int tn  = bid % 8;
  const int tm  = bid / 8;
  const unsigned short* Bptr = W + (size_t)tn * 128 * 1024;

  const int lane = t & 63;
  const int wv   = t >> 6;
  const int wm   = (wv >> 1) * 64;
  const int wn   = (wv & 1) * 64;
  const int fr   = lane & 15;
  const int kq   = (lane >> 4) * 8;

  f32x4 acc[4][4];
#pragma unroll
  for (int i = 0; i < 4; i++)
#pragma unroll
    for (int j = 0; j < 4; j++) acc[i][j] = (f32x4){0.f, 0.f, 0.f, 0.f};

  const int sr = t >> 2;
  const int sc = (t & 3) << 3;
  const unsigned short* gA = A + (size_t)(tm * 128 + sr) * 1024 + sc;
  const unsigned short* gB = Bptr + (size_t)sr * 1024 + sc;
  unsigned short* lA = Alds + t * 8;
  unsigned short* lB = Blds + t * 8;

  for (int k0 = 0; k0 < 1024; k0 += 32) {
    gld_lds16(gA, lA);
    gld_lds16(gA + 64 * 1024, lA + 64 * 32);
    gld_lds16(gB, lB);
    gld_lds16(gB + 64 * 1024, lB + 64 * 32);
    gA += 32; gB += 32;
    __syncthreads();
    bf16x8 af[4], bfr[4];
#pragma unroll
    for (int i = 0; i < 4; i++) {
      af[i]  = *(const bf16x8*)&Alds[(wm + i * 16 + fr) * 32 + kq];
      bfr[i] = *(const bf16x8*)&Blds[(wn + i * 16 + fr) * 32 + kq];
    }
#pragma unroll
    for (int i = 0; i < 4; i++)
#pragma unroll
      for (int j = 0; j < 4; j++)
        acc[i][j] = __builtin_amdgcn_mfma_f32_16x16x32_bf16(af[i], bfr[j], acc[i][j], 0, 0, 0);
    __syncthreads();
  }

  const int quad = lane >> 4;
  const int cc   = lane & 15;
#pragma unroll
  for (int i = 0; i < 4; i++)
#pragma unroll
    for (int j = 0; j < 4; j++)
#pragma unroll
      for (int r = 0; r < 4; r++) {
        int row = tm * 128 + wm + i * 16 + quad * 4 + r;
        int col = tn * 128 + wn + j * 16 + cc;
        out[(size_t)row * 1024 + col] =
            acc[i][j][r] + bp[col] + qres[(size_t)row * 1024 + col];
      }
}

// ---------- kernel 6: in-place LayerNorm ----------
__global__ __launch_bounds__(256) void ln_kernel(float* __restrict__ out,
                                                 const float* __restrict__ gamma,
                                                 const float* __restrict__ beta) {
  __shared__ float red[8];
  const int row = blockIdx.x;
  float* p = out + (size_t)row * 1024;
  const int t = threadIdx.x;
  float4 v = ((const float4*)p)[t];
  float s  = v.x + v.y + v.z + v.w;
  float s2 = v.x * v.x + v.y * v.y + v.z * v.z + v.w * v.w;
#pragma unroll
  for (int off = 1; off < 64; off <<= 1) {
    s  += __shfl_xor(s, off);
    s2 += __shfl_xor(s2, off);
  }
  const int wv = t >> 6;
  if ((t & 63) == 0) { red[wv] = s; red[4 + wv] = s2; }
  __syncthreads();
  float S  = red[0] + red[1] + red[2] + red[3];
  float S2 = red[4] + red[5] + red[6] + red[7];
  float mu  = S * (1.f / 1024.f);
  float var = S2 * (1.f / 1024.f) - mu * mu;
  float rstd = rsqrtf(var + 1e-5f);
  float4 gm = ((const float4*)gamma)[t];
  float4 bt = ((const float4*)beta)[t];
  v.x = (v.x - mu) * rstd * gm.x + bt.x;
  v.y = (v.y - mu) * rstd * gm.y + bt.y;
  v.z = (v.z - mu) * rstd * gm.z + bt.z;
  v.w = (v.w - mu) * rstd * gm.w + bt.w;
  ((float4*)p)[t] = v;
}

// ---------- launch ----------
extern "C" void kernel_launch(void* const* d_in, const int* in_sizes, int n_in,
                              void* d_out, int out_size, void* d_ws, size_t ws_size,
                              hipStream_t stream) {
  const float* query = (const float*)d_in[0];
  const float* keys  = (const float*)d_in[1];
  const float* Wq    = (const float*)d_in[2];
  const float* Wk    = (const float*)d_in[3];
  const float* Wv    = (const float*)d_in[4];
  const float* Wp    = (const float*)d_in[5];
  const float* bp    = (const float*)d_in[6];
  const float* gamma = (const float*)d_in[7];
  const float* beta  = (const float*)d_in[8];
  float* out = (float*)d_out;

  unsigned short* ws   = (unsigned short*)d_ws;
  unsigned short* qb   = ws;                 // 16777216
  unsigned short* kb   = ws + 16777216;      // 16777216
  unsigned short* Wqkv = ws + 33554432;      // 3145728
  unsigned short* Wpb  = ws + 36700160;      // 1048576
  unsigned short* Qb   = ws + 37748736;      // 16777216
  unsigned short* Kb   = ws + 54525952;      // 16777216
  unsigned short* Vb   = ws + 71303168;      // 16777216
  unsigned short* Vtb  = kb;                 // reuse (kb dead after QKV GEMM)
  unsigned short* ctx  = qb;                 // reuse (qb dead after QKV GEMM)

  convert_kernel<<<36864, 256, 0, stream>>>(query, keys, Wq, Wk, Wv, Wp, qb, kb, Wqkv, Wpb);
  gemm_qkv_kernel<<<3072, 256, 0, stream>>>(qb, kb, Wqkv, Qb, Kb, Vb);
  vtrans_kernel<<<1024, 256, 0, stream>>>(Vb, Vtb);
  attn_kernel<<<1024, 256, 0, stream>>>(Qb, Kb, Vtb, ctx);
  gemm_proj_kernel<<<1024, 256, 0, stream>>>(ctx, Wpb, bp, query, out);
  ln_kernel<<<16384, 256, 0, stream>>>(out, gamma, beta);
}

// Round 2
// 565.361 us; speedup vs baseline: 1.1478x; 1.0609x over previous
//
#include <hip/hip_runtime.h>

typedef __bf16 bf16x8 __attribute__((ext_vector_type(8)));
typedef float f32x4 __attribute__((ext_vector_type(4)));

#define SCLOG 0.04508422f   // (1024^-0.5) * log2(e)

// ---------- helpers ----------
__device__ __forceinline__ unsigned short f2bf(float f) {
  union { float f; unsigned int u; } v;
  v.f = f;
  unsigned int u = v.u;
  u += 0x7fffu + ((u >> 16) & 1u);   // RNE
  return (unsigned short)(u >> 16);
}

__device__ __forceinline__ unsigned asuint(float f) {
  union { float f; unsigned u; } v; v.f = f; return v.u;
}

__device__ __forceinline__ void gld_lds16(const void* g, void* l) {
  __builtin_amdgcn_global_load_lds(
      (const __attribute__((address_space(1))) void*)g,
      (__attribute__((address_space(3))) void*)l, 16, 0, 0);
}

// ---------- kernel 1: fp32 -> bf16 conversion ----------
__global__ __launch_bounds__(256) void convert_kernel(
    const float* __restrict__ q, const float* __restrict__ k,
    const float* __restrict__ wq, const float* __restrict__ wk,
    const float* __restrict__ wv, const float* __restrict__ wp,
    unsigned short* __restrict__ qb, unsigned short* __restrict__ kb,
    unsigned short* __restrict__ Wqkv, unsigned short* __restrict__ Wpb) {
  size_t i = (size_t)blockIdx.x * 256 + threadIdx.x;
  const float* src; unsigned short* dst; size_t off;
  if (i < 4194304)      { src = q;  dst = qb;             off = i; }
  else if (i < 8388608) { src = k;  dst = kb;             off = i - 4194304; }
  else if (i < 8650752) { src = wq; dst = Wqkv;           off = i - 8388608; }
  else if (i < 8912896) { src = wk; dst = Wqkv + 1048576; off = i - 8650752; }
  else if (i < 9175040) { src = wv; dst = Wqkv + 2097152; off = i - 8912896; }
  else                  { src = wp; dst = Wpb;            off = i - 9175040; }
  float4 v = ((const float4*)src)[off];
  ushort4 o;
  o.x = f2bf(v.x); o.y = f2bf(v.y); o.z = f2bf(v.z); o.w = f2bf(v.w);
  ((ushort4*)dst)[off] = o;
}

// ---------- kernel 2 v2: fused QKV GEMM, 256x256 tile, BK=64, 8-phase ----------
// 8 waves (2M x 4N), 512 threads, 128KB LDS double-buffer, counted vmcnt(8),
// raw s_barrier (no vmcnt0 drain), setprio around MFMA clusters,
// (row&7)<<4 XOR swizzle (linear gld_lds dest + pre-swizzled global source).
#define QKV_BAR __builtin_amdgcn_s_barrier()
#define QKV_LGKM asm volatile("s_waitcnt lgkmcnt(0)" ::: "memory")

#define QKV_STG(lc, h, srcb, s)                                               \
  gld_lds16((srcb) + (size_t)(s) * 128 + gro0, (lc) + (h) * 16384 + d0);      \
  gld_lds16((srcb) + (size_t)(s) * 128 + gro1, (lc) + (h) * 16384 + d0 + 1024);

#define QKV_RDA(I0)                                                           \
  _Pragma("unroll") for (int i4 = 0; i4 < 4; ++i4) {                          \
    af[i4][0] = *(const bf16x8*)(tb + rbA + ((I0) + i4) * 2048 + cx0);        \
    af[i4][1] = *(const bf16x8*)(tb + rbA + ((I0) + i4) * 2048 + cx1);        \
  }

#define QKV_RDB(JP)                                                           \
  _Pragma("unroll") for (int j2 = 0; j2 < 2; ++j2) {                          \
    bfr[JP][j2][0] = *(const bf16x8*)(tb + rbB + ((JP) * 2 + j2) * 2048 + cx0); \
    bfr[JP][j2][1] = *(const bf16x8*)(tb + rbB + ((JP) * 2 + j2) * 2048 + cx1); \
  }

#define QKV_MM(I0, JP)                                                        \
  _Pragma("unroll") for (int i4 = 0; i4 < 4; ++i4)                            \
  _Pragma("unroll") for (int j2 = 0; j2 < 2; ++j2)                            \
  _Pragma("unroll") for (int kk = 0; kk < 2; ++kk)                            \
    acc[(I0) + i4][(JP) * 2 + j2] = __builtin_amdgcn_mfma_f32_16x16x32_bf16(  \
        af[i4][kk], bfr[JP][j2][kk], acc[(I0) + i4][(JP) * 2 + j2], 0, 0, 0);

__global__ __launch_bounds__(512, 2) void gemm_qkv8_kernel(
    const unsigned short* __restrict__ qb,
    const unsigned short* __restrict__ kb,
    const unsigned short* __restrict__ W,       // [3072][1024]
    unsigned short* __restrict__ Qo,
    unsigned short* __restrict__ Ko,
    unsigned short* __restrict__ Vo) {
  __shared__ char lds[131072];   // buf c at c*65536: A [256][64] 32KB, B at +32768

  const int t = threadIdx.x;
  const int lane = t & 63;
  const int w = t >> 6;            // 0..7
  const int fr = lane & 15;
  const int quad = lane >> 4;

  // bijective XCD swizzle (768 = 8*96): per XCD 8 consecutive tm x all 12 tn
  const int orig = blockIdx.x;
  const int sseq = orig >> 3;                  // 0..95
  const int tn = sseq >> 3;                    // 0..11
  const int tm = (orig & 7) * 8 + (sseq & 7);  // 0..63

  const unsigned short* Ap = (tn < 4) ? qb : kb;
  const char* aBase = (const char*)Ap + (size_t)(tm * 256) * 2048;
  const char* bBase = (const char*)W + (size_t)(tn * 256) * 2048;

  const int wm2 = w >> 2, wn4 = w & 3;

  // staging: thread stages global (row = w*16+qi*8+(lane>>3), colB = ((lane&7)^(lane>>3))*16)
  // to linear LDS slot w*2048+qi*1024+lane*16 -> read-side XOR (row&7)<<4 recovers it.
  const size_t gro0 = (size_t)(w * 16 + (lane >> 3)) * 2048 + (size_t)(((lane & 7) ^ (lane >> 3)) << 4);
  const size_t gro1 = gro0 + 8 * 2048;
  const int d0 = w * 2048 + lane * 16;

  // fragment-read geometry (swizzled)
  const int rbA = (wm2 * 128 + fr) * 128;
  const int rbB = 32768 + (wn4 * 64 + fr) * 128;
  const int cx0 = (quad * 16) ^ ((fr & 7) << 4);
  const int cx1 = cx0 ^ 64;

  f32x4 acc[8][4];
#pragma unroll
  for (int i = 0; i < 8; ++i)
#pragma unroll
    for (int j = 0; j < 4; ++j) acc[i][j] = (f32x4){0.f, 0.f, 0.f, 0.f};

  // prologue: tile0 -> buf0, tile1 -> buf1 (16 loads), release tile0
#pragma unroll
  for (int s = 0; s < 2; ++s) {
    char* lc = lds + s * 65536;
    QKV_STG(lc, 0, aBase, s);
    QKV_STG(lc, 1, aBase + 262144, s);
    QKV_STG(lc + 32768, 0, bBase, s);
    QKV_STG(lc + 32768, 1, bBase + 262144, s);
  }
  asm volatile("s_waitcnt vmcnt(8)" ::: "memory");
  QKV_BAR;

#pragma unroll 1
  for (int kt = 0; kt < 16; ++kt) {
    const char* tb = lds + (kt & 1) * 65536;
    char* lc = lds + (kt & 1) * 65536;
    const int s = kt + 2;
    bf16x8 af[4][2], bfr[2][2][2];

    // ph0: read A-sub0 + B-pair0; MFMA (i0..3, j0..1)
    QKV_RDA(0);
    QKV_RDB(0);
    QKV_BAR; QKV_LGKM;
    __builtin_amdgcn_s_setprio(1);
    QKV_MM(0, 0);
    __builtin_amdgcn_s_setprio(0);
    QKV_BAR;

    // ph1: read B-pair1; MFMA (i0..3, j2..3)
    QKV_RDB(1);
    QKV_BAR; QKV_LGKM;
    __builtin_amdgcn_s_setprio(1);
    QKV_MM(0, 1);
    __builtin_amdgcn_s_setprio(0);
    QKV_BAR;

    // ph2: read A-sub1; stage B halves of tile kt+2 (B LDS free after ph1 bar)
    QKV_RDA(4);
    if (s < 16) {
      QKV_STG(lc + 32768, 0, bBase, s);
      QKV_STG(lc + 32768, 1, bBase + 262144, s);
    }
    QKV_BAR; QKV_LGKM;
    __builtin_amdgcn_s_setprio(1);
    QKV_MM(4, 1);
    __builtin_amdgcn_s_setprio(0);
    QKV_BAR;

    // ph3: stage A halves of tile kt+2 (A LDS free after ph2 bar); MFMA (i4..7, j0..1)
    if (s < 16) {
      QKV_STG(lc, 0, aBase, s);
      QKV_STG(lc, 1, aBase + 262144, s);
    }
    QKV_BAR;
    __builtin_amdgcn_s_setprio(1);
    QKV_MM(4, 0);
    __builtin_amdgcn_s_setprio(0);
    // tile boundary: ensure tile kt+1 resident; keep kt+2's 8 loads in flight
    if (kt <= 13)      { asm volatile("s_waitcnt vmcnt(8)" ::: "memory"); }
    else if (kt == 14) { asm volatile("s_waitcnt vmcnt(0)" ::: "memory"); }
    if (kt < 15) QKV_BAR;
  }

  // epilogue: C[row = M-frag, col = N-frag], 16x16 C-layout (col=lane&15, row=quad*4+r)
  const int sel = tn >> 2;  // 0=Q 1=K 2=V
  unsigned short* Out = sel == 0 ? Qo : (sel == 1 ? Ko : Vo);
  const int row0 = tm * 256 + wm2 * 128 + quad * 4;
  const int col0 = (tn & 3) * 256 + wn4 * 64 + fr;
#pragma unroll
  for (int i = 0; i < 8; ++i)
#pragma unroll
    for (int j = 0; j < 4; ++j)
#pragma unroll
      for (int r = 0; r < 4; ++r)
        Out[(size_t)(row0 + i * 16 + r) * 1024 + col0 + j * 16] = f2bf(acc[i][j][r]);
}

// ---------- kernel 3: per-group V transpose (round-1 proven) ----------
__global__ __launch_bounds__(256) void vtrans_kernel(
    const unsigned short* __restrict__ V, unsigned short* __restrict__ Vt) {
  __shared__ unsigned short T[128 * 136];
  const int g  = blockIdx.x >> 4;
  const int kt = blockIdx.x & 15;
  const unsigned short* Vg = V + (size_t)g * 262144 + (size_t)kt * 128 * 128;
  unsigned short* Vtg = Vt + (size_t)g * 262144 + kt * 128;
  const int t = threadIdx.x;
#pragma unroll
  for (int it = 0; it < 8; it++) {
    int seg = t + it * 256;
    int k  = seg >> 4;
    int c8 = (seg & 15) << 3;
    uint4 a = *(const uint4*)(Vg + k * 128 + c8);
    unsigned short* Tp = &T[c8 * 136 + k];
    Tp[0 * 136] = (unsigned short)(a.x & 0xffff);
    Tp[1 * 136] = (unsigned short)(a.x >> 16);
    Tp[2 * 136] = (unsigned short)(a.y & 0xffff);
    Tp[3 * 136] = (unsigned short)(a.y >> 16);
    Tp[4 * 136] = (unsigned short)(a.z & 0xffff);
    Tp[5 * 136] = (unsigned short)(a.z >> 16);
    Tp[6 * 136] = (unsigned short)(a.w & 0xffff);
    Tp[7 * 136] = (unsigned short)(a.w >> 16);
  }
  __syncthreads();
#pragma unroll
  for (int it = 0; it < 8; it++) {
    int seg = t + it * 256;
    int c  = seg >> 4;
    int k8 = (seg & 15) << 3;
    uint4 o = *(const uint4*)&T[c * 136 + k8];
    *(uint4*)(Vtg + (size_t)c * 2048 + k8) = o;
  }
}

// ---------- kernel 4: flash attention (round-1 proven: dbuf K/V, 1 barrier/tile) ----------
__global__ __launch_bounds__(256, 2) void attn_kernel(
    const unsigned short* __restrict__ Q,
    const unsigned short* __restrict__ K,
    const unsigned short* __restrict__ Vt,   // bf16 [64][128 chunk][2048 key]
    unsigned short* __restrict__ ctx) {
  __shared__ unsigned char smem[81920];
  unsigned char* Psh = smem + 65536;

  const int g  = blockIdx.x >> 4;
  const int qt = blockIdx.x & 15;
  const unsigned short* Qg = Q + (size_t)g * 262144 + (size_t)qt * 16384;
  const unsigned short* Kg = K + (size_t)g * 262144;
  const unsigned short* Vg = Vt + (size_t)g * 262144;   // [128][2048]

  const int t    = threadIdx.x;
  const int lane = t & 63;
  const int wv   = t >> 6;
  const int fr   = lane & 15;
  const int quad = lane >> 4;

  // stage Q [128 rows x 256B] swizzled into smem[0..32768)
#pragma unroll
  for (int it = 0; it < 8; it++) {
    int seg = t + it * 256;
    int r = seg >> 4, p = seg & 15;
    int c = (p & 8) | ((p ^ r) & 7);
    gld_lds16(Qg + r * 128 + c * 8, smem + seg * 16);
  }
  __syncthreads();
  bf16x8 qf[2][4];
#pragma unroll
  for (int nt = 0; nt < 2; nt++)
#pragma unroll
    for (int kc = 0; kc < 4; kc++) {
      int row = wv * 32 + nt * 16 + fr;
      int c = kc * 4 + quad;
      int p = (c & 8) | ((c ^ (row & 7)) & 7);
      qf[nt][kc] = *(const bf16x8*)(smem + row * 256 + p * 16);
    }
  __syncthreads();

  // prologue: stage tile 0 into buffer 0
#pragma unroll
  for (int it = 0; it < 4; it++) {
    int seg = t + it * 256;
    int r = seg >> 4, p = seg & 15;
    int c = (p & 8) | ((p ^ r) & 7);
    gld_lds16(Kg + (size_t)r * 128 + c * 8, smem + seg * 16);
  }
#pragma unroll
  for (int it = 0; it < 4; it++) {
    int seg = t + it * 256;
    int r = seg >> 3, p = seg & 7;
    int c = p ^ (r & 7);
    gld_lds16(Vg + (size_t)r * 2048 + c * 8, smem + 32768 + seg * 16);
  }
  __syncthreads();

  f32x4 O[2][8];
#pragma unroll
  for (int qb2 = 0; qb2 < 2; qb2++)
#pragma unroll
    for (int cb = 0; cb < 8; cb++) O[qb2][cb] = (f32x4){0.f, 0.f, 0.f, 0.f};
  float lp[2] = {0.f, 0.f};

#pragma unroll 1
  for (int kt = 0; kt < 32; kt++) {
    unsigned char* Ksh = smem + (unsigned)(kt & 1) * 16384;
    unsigned char* Vsh = smem + 32768 + (unsigned)(kt & 1) * 16384;

    if (kt < 31) {
      unsigned char* Kst = smem + (unsigned)((kt + 1) & 1) * 16384;
      unsigned char* Vst = smem + 32768 + (unsigned)((kt + 1) & 1) * 16384;
#pragma unroll
      for (int it = 0; it < 4; it++) {
        int seg = t + it * 256;
        int r = seg >> 4, p = seg & 15;
        int c = (p & 8) | ((p ^ r) & 7);
        gld_lds16(Kg + (size_t)((kt + 1) * 64 + r) * 128 + c * 8, Kst + seg * 16);
      }
#pragma unroll
      for (int it = 0; it < 4; it++) {
        int seg = t + it * 256;
        int r = seg >> 3, p = seg & 7;
        int c = p ^ (r & 7);
        gld_lds16(Vg + (size_t)r * 2048 + (kt + 1) * 64 + c * 8, Vst + seg * 16);
      }
    }

    // S^T = K Q^T; in-lane softmax; pack bf16 P
#pragma unroll
    for (int mt = 0; mt < 4; mt++) {
      bf16x8 kf[4];
#pragma unroll
      for (int kc = 0; kc < 4; kc++) {
        int row = mt * 16 + fr;
        int c = kc * 4 + quad;
        int p = (c & 8) | ((c ^ (row & 7)) & 7);
        kf[kc] = *(const bf16x8*)(Ksh + row * 256 + p * 16);
      }
#pragma unroll
      for (int nt = 0; nt < 2; nt++) {
        f32x4 s = (f32x4){0.f, 0.f, 0.f, 0.f};
#pragma unroll
        for (int kc = 0; kc < 4; kc++)
          s = __builtin_amdgcn_mfma_f32_16x16x32_bf16(kf[kc], qf[nt][kc], s, 0, 0, 0);
        float p0 = exp2f(fminf(s[0] * SCLOG, 30.f));
        float p1 = exp2f(fminf(s[1] * SCLOG, 30.f));
        float p2 = exp2f(fminf(s[2] * SCLOG, 30.f));
        float p3 = exp2f(fminf(s[3] * SCLOG, 30.f));
        lp[nt] += (p0 + p1) + (p2 + p3);
        unsigned u01 = __builtin_amdgcn_perm(asuint(p1) + 0x8000u, asuint(p0) + 0x8000u, 0x07060302u);
        unsigned u23 = __builtin_amdgcn_perm(asuint(p3) + 0x8000u, asuint(p2) + 0x8000u, 0x07060302u);
        int qrow = wv * 32 + nt * 16 + fr;
        int cP = mt * 2 + (quad >> 1);
        int pP = cP ^ (qrow & 7);
        uint2 u2; u2.x = u01; u2.y = u23;
        *(uint2*)(Psh + qrow * 128 + pP * 16 + (quad & 1) * 8) = u2;
      }
    }

    // O += P @ V
    bf16x8 pf[2][2];
#pragma unroll
    for (int qb2 = 0; qb2 < 2; qb2++)
#pragma unroll
      for (int k2 = 0; k2 < 2; k2++) {
        int qrow = wv * 32 + qb2 * 16 + fr;
        int c = k2 * 4 + quad;
        int p = c ^ (qrow & 7);
        pf[qb2][k2] = *(const bf16x8*)(Psh + qrow * 128 + p * 16);
      }
#pragma unroll
    for (int cb = 0; cb < 8; cb++)
#pragma unroll
      for (int k2 = 0; k2 < 2; k2++) {
        int crow = cb * 16 + fr;
        int c = k2 * 4 + quad;
        int p = c ^ (crow & 7);
        bf16x8 vf = *(const bf16x8*)(Vsh + crow * 128 + p * 16);
#pragma unroll
        for (int qb2 = 0; qb2 < 2; qb2++)
          O[qb2][cb] = __builtin_amdgcn_mfma_f32_16x16x32_bf16(pf[qb2][k2], vf, O[qb2][cb], 0, 0, 0);
      }

    __syncthreads();
  }

  float* linv_arr = (float*)(smem + 65536);
#pragma unroll
  for (int nt = 0; nt < 2; nt++) {
    float v = lp[nt];
    v += __shfl_xor(v, 16);
    v += __shfl_xor(v, 32);
    if (quad == 0) linv_arr[wv * 32 + nt * 16 + fr] = 1.f / v;
  }
  unsigned short* Cg = ctx + (size_t)g * 262144 + (size_t)qt * 16384;
#pragma unroll
  for (int qb2 = 0; qb2 < 2; qb2++) {
    float li[4];
#pragma unroll
    for (int r = 0; r < 4; r++) li[r] = linv_arr[wv * 32 + qb2 * 16 + quad * 4 + r];
#pragma unroll
    for (int cb = 0; cb < 8; cb++)
#pragma unroll
      for (int r = 0; r < 4; r++) {
        int qrow = wv * 32 + qb2 * 16 + quad * 4 + r;
        Cg[(size_t)qrow * 128 + cb * 16 + fr] = f2bf(O[qb2][cb][r] * li[r]);
      }
  }
}

// ---------- kernel 5: output projection + bias + residual ----------
__global__ __launch_bounds__(256) void gemm_proj_kernel(
    const unsigned short* __restrict__ A,
    const unsigned short* __restrict__ W,
    const float* __restrict__ bp,
    const float* __restrict__ qres,
    float* __restrict__ out) {
  __shared__ unsigned short Alds[128 * 32];
  __shared__ unsigned short Blds[128 * 32];
  const int t   = threadIdx.x;
  const int bid = blockIdx.x;
  const int tn  = bid % 8;
  const int tm  = bid / 8;
  const unsigned short* Bptr = W + (size_t)tn * 128 * 1024;

  const int lane = t & 63;
  const int wv   = t >> 6;
  const int wm   = (wv >> 1) * 64;
  const int wn   = (wv & 1) * 64;
  const int fr   = lane & 15;
  const int kq   = (lane >> 4) * 8;

  f32x4 acc[4][4];
#pragma unroll
  for (int i = 0; i < 4; i++)
#pragma unroll
    for (int j = 0; j < 4; j++) acc[i][j] = (f32x4){0.f, 0.f, 0.f, 0.f};

  const int sr = t >> 2;
  const int sc = (t & 3) << 3;
  const unsigned short* gA = A + (size_t)(tm * 128 + sr) * 1024 + sc;
  const unsigned short* gB = Bptr + (size_t)sr * 1024 + sc;
  unsigned short* lA = Alds + t * 8;
  unsigned short* lB = Blds + t * 8;

  for (int k0 = 0; k0 < 1024; k0 += 32) {
    gld_lds16(gA, lA);
    gld_lds16(gA + 64 * 1024, lA + 64 * 32);
    gld_lds16(gB, lB);
    gld_lds16(gB + 64 * 1024, lB + 64 * 32);
    gA += 32; gB += 32;
    __syncthreads();
    bf16x8 af[4], bfr[4];
#pragma unroll
    for (int i = 0; i < 4; i++) {
      af[i]  = *(const bf16x8*)&Alds[(wm + i * 16 + fr) * 32 + kq];
      bfr[i] = *(const bf16x8*)&Blds[(wn + i * 16 + fr) * 32 + kq];
    }
#pragma unroll
    for (int i = 0; i < 4; i++)
#pragma unroll
      for (int j = 0; j < 4; j++)
        acc[i][j] = __builtin_amdgcn_mfma_f32_16x16x32_bf16(af[i], bfr[j], acc[i][j], 0, 0, 0);
    __syncthreads();
  }

  const int quad = lane >> 4;
  const int cc   = lane & 15;
#pragma unroll
  for (int i = 0; i < 4; i++)
#pragma unroll
    for (int j = 0; j < 4; j++)
#pragma unroll
      for (int r = 0; r < 4; r++) {
        int row = tm * 128 + wm + i * 16 + quad * 4 + r;
        int col = tn * 128 + wn + j * 16 + cc;
        out[(size_t)row * 1024 + col] =
            acc[i][j][r] + bp[col] + qres[(size_t)row * 1024 + col];
      }
}

// ---------- kernel 6: in-place LayerNorm ----------
__global__ __launch_bounds__(256) void ln_kernel(float* __restrict__ out,
                                                 const float* __restrict__ gamma,
                                                 const float* __restrict__ beta) {
  __shared__ float red[8];
  const int row = blockIdx.x;
  float* p = out + (size_t)row * 1024;
  const int t = threadIdx.x;
  float4 v = ((const float4*)p)[t];
  float s  = v.x + v.y + v.z + v.w;
  float s2 = v.x * v.x + v.y * v.y + v.z * v.z + v.w * v.w;
#pragma unroll
  for (int off = 1; off < 64; off <<= 1) {
    s  += __shfl_xor(s, off);
    s2 += __shfl_xor(s2, off);
  }
  const int wv = t >> 6;
  if ((t & 63) == 0) { red[wv] = s; red[4 + wv] = s2; }
  __syncthreads();
  float S  = red[0] + red[1] + red[2] + red[3];
  float S2 = red[4] + red[5] + red[6] + red[7];
  float mu  = S * (1.f / 1024.f);
  float var = S2 * (1.f / 1024.f) - mu * mu;
  float rstd = rsqrtf(var + 1e-5f);
  float4 gm = ((const float4*)gamma)[t];
  float4 bt = ((const float4*)beta)[t];
  v.x = (v.x - mu) * rstd * gm.x + bt.x;
  v.y = (v.y - mu) * rstd * gm.y + bt.y;
  v.z = (v.z - mu) * rstd * gm.z + bt.z;
  v.w = (v.w - mu) * rstd * gm.w + bt.w;
  ((float4*)p)[t] = v;
}

// ---------- launch ----------
extern "C" void kernel_launch(void* const* d_in, const int* in_sizes, int n_in,
                              void* d_out, int out_size, void* d_ws, size_t ws_size,
                              hipStream_t stream) {
  const float* query = (const float*)d_in[0];
  const float* keys  = (const float*)d_in[1];
  const float* Wq    = (const float*)d_in[2];
  const float* Wk    = (const float*)d_in[3];
  const float* Wv    = (const float*)d_in[4];
  const float* Wp    = (const float*)d_in[5];
  const float* bp    = (const float*)d_in[6];
  const float* gamma = (const float*)d_in[7];
  const float* beta  = (const float*)d_in[8];
  float* out = (float*)d_out;

  unsigned short* ws   = (unsigned short*)d_ws;
  unsigned short* qb   = ws;                 // 16777216
  unsigned short* kb   = ws + 16777216;      // 16777216
  unsigned short* Wqkv = ws + 33554432;      // 3145728
  unsigned short* Wpb  = ws + 36700160;      // 1048576
  unsigned short* Qb   = ws + 37748736;      // 16777216
  unsigned short* Kb   = ws + 54525952;      // 16777216
  unsigned short* Vb   = ws + 71303168;      // 16777216
  unsigned short* Vtb  = kb;                 // reuse (kb dead after QKV GEMM)
  unsigned short* ctx  = qb;                 // reuse (qb dead after QKV GEMM)

  convert_kernel<<<36864, 256, 0, stream>>>(query, keys, Wq, Wk, Wv, Wp, qb, kb, Wqkv, Wpb);
  gemm_qkv8_kernel<<<768, 512, 0, stream>>>(qb, kb, Wqkv, Qb, Kb, Vb);
  vtrans_kernel<<<1024, 256, 0, stream>>>(Vb, Vtb);
  attn_kernel<<<1024, 256, 0, stream>>>(Qb, Kb, Vtb, ctx);
  gemm_proj_kernel<<<1024, 256, 0, stream>>>(ctx, Wpb, bp, query, out);
  ln_kernel<<<16384, 256, 0, stream>>>(out, gamma, beta);
}

// Round 3
// 564.473 us; speedup vs baseline: 1.1496x; 1.0016x over previous
//
#include <hip/hip_runtime.h>

typedef __bf16 bf16x8 __attribute__((ext_vector_type(8)));
typedef float f32x4 __attribute__((ext_vector_type(4)));

#define SCLOG 0.04508422f   // (1024^-0.5) * log2(e)

// ---------- helpers ----------
__device__ __forceinline__ unsigned short f2bf(float f) {
  union { float f; unsigned int u; } v;
  v.f = f;
  unsigned int u = v.u;
  u += 0x7fffu + ((u >> 16) & 1u);   // RNE
  return (unsigned short)(u >> 16);
}

__device__ __forceinline__ unsigned asuint(float f) {
  union { float f; unsigned u; } v; v.f = f; return v.u;
}

__device__ __forceinline__ void gld_lds16(const void* g, void* l) {
  __builtin_amdgcn_global_load_lds(
      (const __attribute__((address_space(1))) void*)g,
      (__attribute__((address_space(3))) void*)l, 16, 0, 0);
}

// ---------- kernel 1: fp32 -> bf16 conversion ----------
__global__ __launch_bounds__(256) void convert_kernel(
    const float* __restrict__ q, const float* __restrict__ k,
    const float* __restrict__ wq, const float* __restrict__ wk,
    const float* __restrict__ wv, const float* __restrict__ wp,
    unsigned short* __restrict__ qb, unsigned short* __restrict__ kb,
    unsigned short* __restrict__ Wqkv, unsigned short* __restrict__ Wpb) {
  size_t i = (size_t)blockIdx.x * 256 + threadIdx.x;
  const float* src; unsigned short* dst; size_t off;
  if (i < 4194304)      { src = q;  dst = qb;             off = i; }
  else if (i < 8388608) { src = k;  dst = kb;             off = i - 4194304; }
  else if (i < 8650752) { src = wq; dst = Wqkv;           off = i - 8388608; }
  else if (i < 8912896) { src = wk; dst = Wqkv + 1048576; off = i - 8650752; }
  else if (i < 9175040) { src = wv; dst = Wqkv + 2097152; off = i - 8912896; }
  else                  { src = wp; dst = Wpb;            off = i - 9175040; }
  float4 v = ((const float4*)src)[off];
  ushort4 o;
  o.x = f2bf(v.x); o.y = f2bf(v.y); o.z = f2bf(v.z); o.w = f2bf(v.w);
  ((ushort4*)dst)[off] = o;
}

// ---------- kernel 2 v2: fused QKV GEMM, 256x256 tile, BK=64, 8-phase ----------
#define QKV_BAR __builtin_amdgcn_s_barrier()
#define QKV_LGKM asm volatile("s_waitcnt lgkmcnt(0)" ::: "memory")

#define QKV_STG(lc, h, srcb, s)                                               \
  gld_lds16((srcb) + (size_t)(s) * 128 + gro0, (lc) + (h) * 16384 + d0);      \
  gld_lds16((srcb) + (size_t)(s) * 128 + gro1, (lc) + (h) * 16384 + d0 + 1024);

#define QKV_RDA(I0)                                                           \
  _Pragma("unroll") for (int i4 = 0; i4 < 4; ++i4) {                          \
    af[i4][0] = *(const bf16x8*)(tb + rbA + ((I0) + i4) * 2048 + cx0);        \
    af[i4][1] = *(const bf16x8*)(tb + rbA + ((I0) + i4) * 2048 + cx1);        \
  }

#define QKV_RDB(JP)                                                           \
  _Pragma("unroll") for (int j2 = 0; j2 < 2; ++j2) {                          \
    bfr[JP][j2][0] = *(const bf16x8*)(tb + rbB + ((JP) * 2 + j2) * 2048 + cx0); \
    bfr[JP][j2][1] = *(const bf16x8*)(tb + rbB + ((JP) * 2 + j2) * 2048 + cx1); \
  }

#define QKV_MM(I0, JP)                                                        \
  _Pragma("unroll") for (int i4 = 0; i4 < 4; ++i4)                            \
  _Pragma("unroll") for (int j2 = 0; j2 < 2; ++j2)                            \
  _Pragma("unroll") for (int kk = 0; kk < 2; ++kk)                            \
    acc[(I0) + i4][(JP) * 2 + j2] = __builtin_amdgcn_mfma_f32_16x16x32_bf16(  \
        af[i4][kk], bfr[JP][j2][kk], acc[(I0) + i4][(JP) * 2 + j2], 0, 0, 0);

__global__ __launch_bounds__(512, 2) void gemm_qkv8_kernel(
    const unsigned short* __restrict__ qb,
    const unsigned short* __restrict__ kb,
    const unsigned short* __restrict__ W,       // [3072][1024]
    unsigned short* __restrict__ Qo,
    unsigned short* __restrict__ Ko,
    unsigned short* __restrict__ Vo) {
  __shared__ char lds[131072];   // buf c at c*65536: A [256][64] 32KB, B at +32768

  const int t = threadIdx.x;
  const int lane = t & 63;
  const int w = t >> 6;            // 0..7
  const int fr = lane & 15;
  const int quad = lane >> 4;

  // bijective XCD swizzle (768 = 8*96): per XCD 8 consecutive tm x all 12 tn
  const int orig = blockIdx.x;
  const int sseq = orig >> 3;                  // 0..95
  const int tn = sseq >> 3;                    // 0..11
  const int tm = (orig & 7) * 8 + (sseq & 7);  // 0..63

  const unsigned short* Ap = (tn < 4) ? qb : kb;
  const char* aBase = (const char*)Ap + (size_t)(tm * 256) * 2048;
  const char* bBase = (const char*)W + (size_t)(tn * 256) * 2048;

  const int wm2 = w >> 2, wn4 = w & 3;

  const size_t gro0 = (size_t)(w * 16 + (lane >> 3)) * 2048 + (size_t)(((lane & 7) ^ (lane >> 3)) << 4);
  const size_t gro1 = gro0 + 8 * 2048;
  const int d0 = w * 2048 + lane * 16;

  const int rbA = (wm2 * 128 + fr) * 128;
  const int rbB = 32768 + (wn4 * 64 + fr) * 128;
  const int cx0 = (quad * 16) ^ ((fr & 7) << 4);
  const int cx1 = cx0 ^ 64;

  f32x4 acc[8][4];
#pragma unroll
  for (int i = 0; i < 8; ++i)
#pragma unroll
    for (int j = 0; j < 4; ++j) acc[i][j] = (f32x4){0.f, 0.f, 0.f, 0.f};

#pragma unroll
  for (int s = 0; s < 2; ++s) {
    char* lc = lds + s * 65536;
    QKV_STG(lc, 0, aBase, s);
    QKV_STG(lc, 1, aBase + 262144, s);
    QKV_STG(lc + 32768, 0, bBase, s);
    QKV_STG(lc + 32768, 1, bBase + 262144, s);
  }
  asm volatile("s_waitcnt vmcnt(8)" ::: "memory");
  QKV_BAR;

#pragma unroll 1
  for (int kt = 0; kt < 16; ++kt) {
    const char* tb = lds + (kt & 1) * 65536;
    char* lc = lds + (kt & 1) * 65536;
    const int s = kt + 2;
    bf16x8 af[4][2], bfr[2][2][2];

    QKV_RDA(0);
    QKV_RDB(0);
    QKV_BAR; QKV_LGKM;
    __builtin_amdgcn_s_setprio(1);
    QKV_MM(0, 0);
    __builtin_amdgcn_s_setprio(0);
    QKV_BAR;

    QKV_RDB(1);
    QKV_BAR; QKV_LGKM;
    __builtin_amdgcn_s_setprio(1);
    QKV_MM(0, 1);
    __builtin_amdgcn_s_setprio(0);
    QKV_BAR;

    QKV_RDA(4);
    if (s < 16) {
      QKV_STG(lc + 32768, 0, bBase, s);
      QKV_STG(lc + 32768, 1, bBase + 262144, s);
    }
    QKV_BAR; QKV_LGKM;
    __builtin_amdgcn_s_setprio(1);
    QKV_MM(4, 1);
    __builtin_amdgcn_s_setprio(0);
    QKV_BAR;

    if (s < 16) {
      QKV_STG(lc, 0, aBase, s);
      QKV_STG(lc, 1, aBase + 262144, s);
    }
    QKV_BAR;
    __builtin_amdgcn_s_setprio(1);
    QKV_MM(4, 0);
    __builtin_amdgcn_s_setprio(0);
    if (kt <= 13)      { asm volatile("s_waitcnt vmcnt(8)" ::: "memory"); }
    else if (kt == 14) { asm volatile("s_waitcnt vmcnt(0)" ::: "memory"); }
    if (kt < 15) QKV_BAR;
  }

  const int sel = tn >> 2;  // 0=Q 1=K 2=V
  unsigned short* Out = sel == 0 ? Qo : (sel == 1 ? Ko : Vo);
  const int row0 = tm * 256 + wm2 * 128 + quad * 4;
  const int col0 = (tn & 3) * 256 + wn4 * 64 + fr;
#pragma unroll
  for (int i = 0; i < 8; ++i)
#pragma unroll
    for (int j = 0; j < 4; ++j)
#pragma unroll
      for (int r = 0; r < 4; ++r)
        Out[(size_t)(row0 + i * 16 + r) * 1024 + col0 + j * 16] = f2bf(acc[i][j][r]);
}

// ---------- kernel 3: per-group V transpose (round-1 proven) ----------
__global__ __launch_bounds__(256) void vtrans_kernel(
    const unsigned short* __restrict__ V, unsigned short* __restrict__ Vt) {
  __shared__ unsigned short T[128 * 136];
  const int g  = blockIdx.x >> 4;
  const int kt = blockIdx.x & 15;
  const unsigned short* Vg = V + (size_t)g * 262144 + (size_t)kt * 128 * 128;
  unsigned short* Vtg = Vt + (size_t)g * 262144 + kt * 128;
  const int t = threadIdx.x;
#pragma unroll
  for (int it = 0; it < 8; it++) {
    int seg = t + it * 256;
    int k  = seg >> 4;
    int c8 = (seg & 15) << 3;
    uint4 a = *(const uint4*)(Vg + k * 128 + c8);
    unsigned short* Tp = &T[c8 * 136 + k];
    Tp[0 * 136] = (unsigned short)(a.x & 0xffff);
    Tp[1 * 136] = (unsigned short)(a.x >> 16);
    Tp[2 * 136] = (unsigned short)(a.y & 0xffff);
    Tp[3 * 136] = (unsigned short)(a.y >> 16);
    Tp[4 * 136] = (unsigned short)(a.z & 0xffff);
    Tp[5 * 136] = (unsigned short)(a.z >> 16);
    Tp[6 * 136] = (unsigned short)(a.w & 0xffff);
    Tp[7 * 136] = (unsigned short)(a.w >> 16);
  }
  __syncthreads();
#pragma unroll
  for (int it = 0; it < 8; it++) {
    int seg = t + it * 256;
    int c  = seg >> 4;
    int k8 = (seg & 15) << 3;
    uint4 o = *(const uint4*)&T[c * 136 + k8];
    *(uint4*)(Vtg + (size_t)c * 2048 + k8) = o;
  }
}

// ---------- kernel 4 v3: flash attention, 8 waves x 16 qrows, dbuf K/V ----------
// Same LDS layout/swizzles/barrier scheme as v2; wave->qrow decomposition
// halved so 2 resident blocks give 16 waves/CU (4/SIMD) instead of 8.
__global__ __launch_bounds__(512, 4) void attn_kernel(
    const unsigned short* __restrict__ Q,
    const unsigned short* __restrict__ K,
    const unsigned short* __restrict__ Vt,   // bf16 [64][128 chunk][2048 key]
    unsigned short* __restrict__ ctx) {
  // Kbuf[b] = smem + b*16384        [64 key][256B], chunk c at p=(c&8)|((c^r)&7)
  // Vbuf[b] = smem + 32768 + b*16384 [128 chunk][128B], chunk c at p=c^(r&7)
  // Psh     = smem + 65536          [128 qrow][128B], chunk c at p=c^(r&7)
  __shared__ unsigned char smem[81920];
  unsigned char* Psh = smem + 65536;

  const int g  = blockIdx.x >> 4;
  const int qt = blockIdx.x & 15;
  const unsigned short* Qg = Q + (size_t)g * 262144 + (size_t)qt * 16384;
  const unsigned short* Kg = K + (size_t)g * 262144;
  const unsigned short* Vg = Vt + (size_t)g * 262144;   // [128][2048]

  const int t    = threadIdx.x;
  const int lane = t & 63;
  const int wv   = t >> 6;          // 0..7, wave owns qrows [wv*16, wv*16+16)
  const int fr   = lane & 15;
  const int quad = lane >> 4;

  // stage Q [128 rows x 256B] swizzled into smem[0..32768)
#pragma unroll
  for (int it = 0; it < 4; it++) {
    int seg = t + it * 512;
    int r = seg >> 4, p = seg & 15;
    int c = (p & 8) | ((p ^ r) & 7);
    gld_lds16(Qg + r * 128 + c * 8, smem + seg * 16);
  }
  __syncthreads();
  bf16x8 qf[4];   // B-frag: Q[qrow = wv*16+fr][k = kc*32+quad*8+j]
#pragma unroll
  for (int kc = 0; kc < 4; kc++) {
    int row = wv * 16 + fr;
    int c = kc * 4 + quad;
    int p = (c & 8) | ((c ^ (row & 7)) & 7);
    qf[kc] = *(const bf16x8*)(smem + row * 256 + p * 16);
  }
  __syncthreads();   // all waves done reading Q region (Kbufs overlay it)

  // prologue: stage tile 0 into buffer 0
#pragma unroll
  for (int it = 0; it < 2; it++) {
    int seg = t + it * 512;
    int r = seg >> 4, p = seg & 15;
    int c = (p & 8) | ((p ^ r) & 7);
    gld_lds16(Kg + (size_t)r * 128 + c * 8, smem + seg * 16);
  }
#pragma unroll
  for (int it = 0; it < 2; it++) {
    int seg = t + it * 512;
    int r = seg >> 3, p = seg & 7;
    int c = p ^ (r & 7);
    gld_lds16(Vg + (size_t)r * 2048 + c * 8, smem + 32768 + seg * 16);
  }
  __syncthreads();

  f32x4 O[8];   // D[qrow][chunk cb]
#pragma unroll
  for (int cb = 0; cb < 8; cb++) O[cb] = (f32x4){0.f, 0.f, 0.f, 0.f};
  float lp = 0.f;

#pragma unroll 1
  for (int kt = 0; kt < 32; kt++) {
    unsigned char* Ksh = smem + (unsigned)(kt & 1) * 16384;
    unsigned char* Vsh = smem + 32768 + (unsigned)(kt & 1) * 16384;

    if (kt < 31) {
      unsigned char* Kst = smem + (unsigned)((kt + 1) & 1) * 16384;
      unsigned char* Vst = smem + 32768 + (unsigned)((kt + 1) & 1) * 16384;
#pragma unroll
      for (int it = 0; it < 2; it++) {
        int seg = t + it * 512;
        int r = seg >> 4, p = seg & 15;
        int c = (p & 8) | ((p ^ r) & 7);
        gld_lds16(Kg + (size_t)((kt + 1) * 64 + r) * 128 + c * 8, Kst + seg * 16);
      }
#pragma unroll
      for (int it = 0; it < 2; it++) {
        int seg = t + it * 512;
        int r = seg >> 3, p = seg & 7;
        int c = p ^ (r & 7);
        gld_lds16(Vg + (size_t)r * 2048 + (kt + 1) * 64 + c * 8, Vst + seg * 16);
      }
    }

    // S^T = K Q^T; in-lane softmax; pack bf16 P
#pragma unroll
    for (int mt = 0; mt < 4; mt++) {
      bf16x8 kf[4];
#pragma unroll
      for (int kc = 0; kc < 4; kc++) {
        int row = mt * 16 + fr;
        int c = kc * 4 + quad;
        int p = (c & 8) | ((c ^ (row & 7)) & 7);
        kf[kc] = *(const bf16x8*)(Ksh + row * 256 + p * 16);
      }
      f32x4 s = (f32x4){0.f, 0.f, 0.f, 0.f};
#pragma unroll
      for (int kc = 0; kc < 4; kc++)
        s = __builtin_amdgcn_mfma_f32_16x16x32_bf16(kf[kc], qf[kc], s, 0, 0, 0);
      // lane holds S^T[key = mt*16+quad*4+r][qrow = wv*16+fr]
      float p0 = exp2f(fminf(s[0] * SCLOG, 30.f));
      float p1 = exp2f(fminf(s[1] * SCLOG, 30.f));
      float p2 = exp2f(fminf(s[2] * SCLOG, 30.f));
      float p3 = exp2f(fminf(s[3] * SCLOG, 30.f));
      lp += (p0 + p1) + (p2 + p3);
      unsigned u01 = __builtin_amdgcn_perm(asuint(p1) + 0x8000u, asuint(p0) + 0x8000u, 0x07060302u);
      unsigned u23 = __builtin_amdgcn_perm(asuint(p3) + 0x8000u, asuint(p2) + 0x8000u, 0x07060302u);
      int qrow = wv * 16 + fr;
      int cP = mt * 2 + (quad >> 1);            // 16B-chunk of keys key0/8
      int pP = cP ^ (qrow & 7);
      uint2 u2; u2.x = u01; u2.y = u23;
      *(uint2*)(Psh + qrow * 128 + pP * 16 + (quad & 1) * 8) = u2;
    }

    // O += P @ V  (P rows wave-private: no barrier needed)
    bf16x8 pf[2];
#pragma unroll
    for (int k2 = 0; k2 < 2; k2++) {
      int qrow = wv * 16 + fr;
      int c = k2 * 4 + quad;
      int p = c ^ (qrow & 7);
      pf[k2] = *(const bf16x8*)(Psh + qrow * 128 + p * 16);
    }
#pragma unroll
    for (int cb = 0; cb < 8; cb++)
#pragma unroll
      for (int k2 = 0; k2 < 2; k2++) {
        int crow = cb * 16 + fr;
        int c = k2 * 4 + quad;
        int p = c ^ (crow & 7);
        bf16x8 vf = *(const bf16x8*)(Vsh + crow * 128 + p * 16);
        O[cb] = __builtin_amdgcn_mfma_f32_16x16x32_bf16(pf[k2], vf, O[cb], 0, 0, 0);
      }

    __syncthreads();
  }

  // row-sum across quads, then normalize + write ctx (linv overlaid on Psh)
  float* linv_arr = (float*)(smem + 65536);
  {
    float v = lp;
    v += __shfl_xor(v, 16);
    v += __shfl_xor(v, 32);
    if (quad == 0) linv_arr[wv * 16 + fr] = 1.f / v;
  }
  unsigned short* Cg = ctx + (size_t)g * 262144 + (size_t)qt * 16384;
  float li[4];
#pragma unroll
  for (int r = 0; r < 4; r++) li[r] = linv_arr[wv * 16 + quad * 4 + r];
#pragma unroll
  for (int cb = 0; cb < 8; cb++)
#pragma unroll
    for (int r = 0; r < 4; r++) {
      int qrow = wv * 16 + quad * 4 + r;
      Cg[(size_t)qrow * 128 + cb * 16 + fr] = f2bf(O[cb][r] * li[r]);
    }
}

// ---------- kernel 5: output projection + bias + residual ----------
__global__ __launch_bounds__(256) void gemm_proj_kernel(
    const unsigned short* __restrict__ A,
    const unsigned short* __restrict__ W,
    const float* __restrict__ bp,
    const float* __restrict__ qres,
    float* __restrict__ out) {
  __shared__ unsigned short Alds[128 * 32];
  __shared__ unsigned short Blds[128 * 32];
  const int t   = threadIdx.x;
  const int bid = blockIdx.x;
  const int tn  = bid % 8;
  const int tm  = bid / 8;
  const unsigned short* Bptr = W + (size_t)tn * 128 * 1024;

  const int lane = t & 63;
  const int wv   = t >> 6;
  const int wm   = (wv >> 1) * 64;
  const int wn   = (wv & 1) * 64;
  const int fr   = lane & 15;
  const int kq   = (lane >> 4) * 8;

  f32x4 acc[4][4];
#pragma unroll
  for (int i = 0; i < 4; i++)
#pragma unroll
    for (int j = 0; j < 4; j++) acc[i][j] = (f32x4){0.f, 0.f, 0.f, 0.f};

  const int sr = t >> 2;
  const int sc = (t & 3) << 3;
  const unsigned short* gA = A + (size_t)(tm * 128 + sr) * 1024 + sc;
  const unsigned short* gB = Bptr + (size_t)sr * 1024 + sc;
  unsigned short* lA = Alds + t * 8;
  unsigned short* lB = Blds + t * 8;

  for (int k0 = 0; k0 < 1024; k0 += 32) {
    gld_lds16(gA, lA);
    gld_lds16(gA + 64 * 1024, lA + 64 * 32);
    gld_lds16(gB, lB);
    gld_lds16(gB + 64 * 1024, lB + 64 * 32);
    gA += 32; gB += 32;
    __syncthreads();
    bf16x8 af[4], bfr[4];
#pragma unroll
    for (int i = 0; i < 4; i++) {
      af[i]  = *(const bf16x8*)&Alds[(wm + i * 16 + fr) * 32 + kq];
      bfr[i] = *(const bf16x8*)&Blds[(wn + i * 16 + fr) * 32 + kq];
    }
#pragma unroll
    for (int i = 0; i < 4; i++)
#pragma unroll
      for (int j = 0; j < 4; j++)
        acc[i][j] = __builtin_amdgcn_mfma_f32_16x16x32_bf16(af[i], bfr[j], acc[i][j], 0, 0, 0);
    __syncthreads();
  }

  const int quad = lane >> 4;
  const int cc   = lane & 15;
#pragma unroll
  for (int i = 0; i < 4; i++)
#pragma unroll
    for (int j = 0; j < 4; j++)
#pragma unroll
      for (int r = 0; r < 4; r++) {
        int row = tm * 128 + wm + i * 16 + quad * 4 + r;
        int col = tn * 128 + wn + j * 16 + cc;
        out[(size_t)row * 1024 + col] =
            acc[i][j][r] + bp[col] + qres[(size_t)row * 1024 + col];
      }
}

// ---------- kernel 6: in-place LayerNorm ----------
__global__ __launch_bounds__(256) void ln_kernel(float* __restrict__ out,
                                                 const float* __restrict__ gamma,
                                                 const float* __restrict__ beta) {
  __shared__ float red[8];
  const int row = blockIdx.x;
  float* p = out + (size_t)row * 1024;
  const int t = threadIdx.x;
  float4 v = ((const float4*)p)[t];
  float s  = v.x + v.y + v.z + v.w;
  float s2 = v.x * v.x + v.y * v.y + v.z * v.z + v.w * v.w;
#pragma unroll
  for (int off = 1; off < 64; off <<= 1) {
    s  += __shfl_xor(s, off);
    s2 += __shfl_xor(s2, off);
  }
  const int wv = t >> 6;
  if ((t & 63) == 0) { red[wv] = s; red[4 + wv] = s2; }
  __syncthreads();
  float S  = red[0] + red[1] + red[2] + red[3];
  float S2 = red[4] + red[5] + red[6] + red[7];
  float mu  = S * (1.f / 1024.f);
  float var = S2 * (1.f / 1024.f) - mu * mu;
  float rstd = rsqrtf(var + 1e-5f);
  float4 gm = ((const float4*)gamma)[t];
  float4 bt = ((const float4*)beta)[t];
  v.x = (v.x - mu) * rstd * gm.x + bt.x;
  v.y = (v.y - mu) * rstd * gm.y + bt.y;
  v.z = (v.z - mu) * rstd * gm.z + bt.z;
  v.w = (v.w - mu) * rstd * gm.w + bt.w;
  ((float4*)p)[t] = v;
}

// ---------- launch ----------
extern "C" void kernel_launch(void* const* d_in, const int* in_sizes, int n_in,
                              void* d_out, int out_size, void* d_ws, size_t ws_size,
                              hipStream_t stream) {
  const float* query = (const float*)d_in[0];
  const float* keys  = (const float*)d_in[1];
  const float* Wq    = (const float*)d_in[2];
  const float* Wk    = (const float*)d_in[3];
  const float* Wv    = (const float*)d_in[4];
  const float* Wp    = (const float*)d_in[5];
  const float* bp    = (const float*)d_in[6];
  const float* gamma = (const float*)d_in[7];
  const float* beta  = (const float*)d_in[8];
  float* out = (float*)d_out;

  unsigned short* ws   = (unsigned short*)d_ws;
  unsigned short* qb   = ws;                 // 16777216
  unsigned short* kb   = ws + 16777216;      // 16777216
  unsigned short* Wqkv = ws + 33554432;      // 3145728
  unsigned short* Wpb  = ws + 36700160;      // 1048576
  unsigned short* Qb   = ws + 37748736;      // 16777216
  unsigned short* Kb   = ws + 54525952;      // 16777216
  unsigned short* Vb   = ws + 71303168;      // 16777216
  unsigned short* Vtb  = kb;                 // reuse (kb dead after QKV GEMM)
  unsigned short* ctx  = qb;                 // reuse (qb dead after QKV GEMM)

  convert_kernel<<<36864, 256, 0, stream>>>(query, keys, Wq, Wk, Wv, Wp, qb, kb, Wqkv, Wpb);
  gemm_qkv8_kernel<<<768, 512, 0, stream>>>(qb, kb, Wqkv, Qb, Kb, Vb);
  vtrans_kernel<<<1024, 256, 0, stream>>>(Vb, Vtb);
  attn_kernel<<<1024, 512, 0, stream>>>(Qb, Kb, Vtb, ctx);
  gemm_proj_kernel<<<1024, 256, 0, stream>>>(ctx, Wpb, bp, query, out);
  ln_kernel<<<16384, 256, 0, stream>>>(out, gamma, beta);
}

// Round 4
// 542.736 us; speedup vs baseline: 1.1956x; 1.0401x over previous
//
#include <hip/hip_runtime.h>

typedef __bf16 bf16x8 __attribute__((ext_vector_type(8)));
typedef float f32x4 __attribute__((ext_vector_type(4)));

#define SCLOG 0.04508422f   // (1024^-0.5) * log2(e)

// ---------- helpers ----------
__device__ __forceinline__ unsigned short f2bf(float f) {
  union { float f; unsigned int u; } v;
  v.f = f;
  unsigned int u = v.u;
  u += 0x7fffu + ((u >> 16) & 1u);   // RNE
  return (unsigned short)(u >> 16);
}

__device__ __forceinline__ void gld_lds16(const void* g, void* l) {
  __builtin_amdgcn_global_load_lds(
      (const __attribute__((address_space(1))) void*)g,
      (__attribute__((address_space(3))) void*)l, 16, 0, 0);
}

// ---------- kernel 1: fp32 -> bf16 conversion ----------
__global__ __launch_bounds__(256) void convert_kernel(
    const float* __restrict__ q, const float* __restrict__ k,
    const float* __restrict__ wq, const float* __restrict__ wk,
    const float* __restrict__ wv, const float* __restrict__ wp,
    unsigned short* __restrict__ qb, unsigned short* __restrict__ kb,
    unsigned short* __restrict__ Wqkv, unsigned short* __restrict__ Wpb) {
  size_t i = (size_t)blockIdx.x * 256 + threadIdx.x;
  const float* src; unsigned short* dst; size_t off;
  if (i < 4194304)      { src = q;  dst = qb;             off = i; }
  else if (i < 8388608) { src = k;  dst = kb;             off = i - 4194304; }
  else if (i < 8650752) { src = wq; dst = Wqkv;           off = i - 8388608; }
  else if (i < 8912896) { src = wk; dst = Wqkv + 1048576; off = i - 8650752; }
  else if (i < 9175040) { src = wv; dst = Wqkv + 2097152; off = i - 8912896; }
  else                  { src = wp; dst = Wpb;            off = i - 9175040; }
  float4 v = ((const float4*)src)[off];
  ushort4 o;
  o.x = f2bf(v.x); o.y = f2bf(v.y); o.z = f2bf(v.z); o.w = f2bf(v.w);
  ((ushort4*)dst)[off] = o;
}

// ---------- kernel 2 v2: fused QKV GEMM, 256x256 tile, BK=64, 8-phase ----------
// v3 change: Q output pre-scaled by SCLOG (softmax scale folded into Q).
#define QKV_BAR __builtin_amdgcn_s_barrier()
#define QKV_LGKM asm volatile("s_waitcnt lgkmcnt(0)" ::: "memory")

#define QKV_STG(lc, h, srcb, s)                                               \
  gld_lds16((srcb) + (size_t)(s) * 128 + gro0, (lc) + (h) * 16384 + d0);      \
  gld_lds16((srcb) + (size_t)(s) * 128 + gro1, (lc) + (h) * 16384 + d0 + 1024);

#define QKV_RDA(I0)                                                           \
  _Pragma("unroll") for (int i4 = 0; i4 < 4; ++i4) {                          \
    af[i4][0] = *(const bf16x8*)(tb + rbA + ((I0) + i4) * 2048 + cx0);        \
    af[i4][1] = *(const bf16x8*)(tb + rbA + ((I0) + i4) * 2048 + cx1);        \
  }

#define QKV_RDB(JP)                                                           \
  _Pragma("unroll") for (int j2 = 0; j2 < 2; ++j2) {                          \
    bfr[JP][j2][0] = *(const bf16x8*)(tb + rbB + ((JP) * 2 + j2) * 2048 + cx0); \
    bfr[JP][j2][1] = *(const bf16x8*)(tb + rbB + ((JP) * 2 + j2) * 2048 + cx1); \
  }

#define QKV_MM(I0, JP)                                                        \
  _Pragma("unroll") for (int i4 = 0; i4 < 4; ++i4)                            \
  _Pragma("unroll") for (int j2 = 0; j2 < 2; ++j2)                            \
  _Pragma("unroll") for (int kk = 0; kk < 2; ++kk)                            \
    acc[(I0) + i4][(JP) * 2 + j2] = __builtin_amdgcn_mfma_f32_16x16x32_bf16(  \
        af[i4][kk], bfr[JP][j2][kk], acc[(I0) + i4][(JP) * 2 + j2], 0, 0, 0);

__global__ __launch_bounds__(512, 2) void gemm_qkv8_kernel(
    const unsigned short* __restrict__ qb,
    const unsigned short* __restrict__ kb,
    const unsigned short* __restrict__ W,       // [3072][1024]
    unsigned short* __restrict__ Qo,
    unsigned short* __restrict__ Ko,
    unsigned short* __restrict__ Vo) {
  __shared__ char lds[131072];   // buf c at c*65536: A [256][64] 32KB, B at +32768

  const int t = threadIdx.x;
  const int lane = t & 63;
  const int w = t >> 6;            // 0..7
  const int fr = lane & 15;
  const int quad = lane >> 4;

  // bijective XCD swizzle (768 = 8*96): per XCD 8 consecutive tm x all 12 tn
  const int orig = blockIdx.x;
  const int sseq = orig >> 3;                  // 0..95
  const int tn = sseq >> 3;                    // 0..11
  const int tm = (orig & 7) * 8 + (sseq & 7);  // 0..63

  const unsigned short* Ap = (tn < 4) ? qb : kb;
  const char* aBase = (const char*)Ap + (size_t)(tm * 256) * 2048;
  const char* bBase = (const char*)W + (size_t)(tn * 256) * 2048;

  const int wm2 = w >> 2, wn4 = w & 3;

  const size_t gro0 = (size_t)(w * 16 + (lane >> 3)) * 2048 + (size_t)(((lane & 7) ^ (lane >> 3)) << 4);
  const size_t gro1 = gro0 + 8 * 2048;
  const int d0 = w * 2048 + lane * 16;

  const int rbA = (wm2 * 128 + fr) * 128;
  const int rbB = 32768 + (wn4 * 64 + fr) * 128;
  const int cx0 = (quad * 16) ^ ((fr & 7) << 4);
  const int cx1 = cx0 ^ 64;

  f32x4 acc[8][4];
#pragma unroll
  for (int i = 0; i < 8; ++i)
#pragma unroll
    for (int j = 0; j < 4; ++j) acc[i][j] = (f32x4){0.f, 0.f, 0.f, 0.f};

#pragma unroll
  for (int s = 0; s < 2; ++s) {
    char* lc = lds + s * 65536;
    QKV_STG(lc, 0, aBase, s);
    QKV_STG(lc, 1, aBase + 262144, s);
    QKV_STG(lc + 32768, 0, bBase, s);
    QKV_STG(lc + 32768, 1, bBase + 262144, s);
  }
  asm volatile("s_waitcnt vmcnt(8)" ::: "memory");
  QKV_BAR;

#pragma unroll 1
  for (int kt = 0; kt < 16; ++kt) {
    const char* tb = lds + (kt & 1) * 65536;
    char* lc = lds + (kt & 1) * 65536;
    const int s = kt + 2;
    bf16x8 af[4][2], bfr[2][2][2];

    QKV_RDA(0);
    QKV_RDB(0);
    QKV_BAR; QKV_LGKM;
    __builtin_amdgcn_s_setprio(1);
    QKV_MM(0, 0);
    __builtin_amdgcn_s_setprio(0);
    QKV_BAR;

    QKV_RDB(1);
    QKV_BAR; QKV_LGKM;
    __builtin_amdgcn_s_setprio(1);
    QKV_MM(0, 1);
    __builtin_amdgcn_s_setprio(0);
    QKV_BAR;

    QKV_RDA(4);
    if (s < 16) {
      QKV_STG(lc + 32768, 0, bBase, s);
      QKV_STG(lc + 32768, 1, bBase + 262144, s);
    }
    QKV_BAR; QKV_LGKM;
    __builtin_amdgcn_s_setprio(1);
    QKV_MM(4, 1);
    __builtin_amdgcn_s_setprio(0);
    QKV_BAR;

    if (s < 16) {
      QKV_STG(lc, 0, aBase, s);
      QKV_STG(lc, 1, aBase + 262144, s);
    }
    QKV_BAR;
    __builtin_amdgcn_s_setprio(1);
    QKV_MM(4, 0);
    __builtin_amdgcn_s_setprio(0);
    if (kt <= 13)      { asm volatile("s_waitcnt vmcnt(8)" ::: "memory"); }
    else if (kt == 14) { asm volatile("s_waitcnt vmcnt(0)" ::: "memory"); }
    if (kt < 15) QKV_BAR;
  }

  const int sel = tn >> 2;  // 0=Q 1=K 2=V
  unsigned short* Out = sel == 0 ? Qo : (sel == 1 ? Ko : Vo);
  const float osc = (sel == 0) ? SCLOG : 1.f;   // fold softmax scale*log2e into Q
  const int row0 = tm * 256 + wm2 * 128 + quad * 4;
  const int col0 = (tn & 3) * 256 + wn4 * 64 + fr;
#pragma unroll
  for (int i = 0; i < 8; ++i)
#pragma unroll
    for (int j = 0; j < 4; ++j)
#pragma unroll
      for (int r = 0; r < 4; ++r)
        Out[(size_t)(row0 + i * 16 + r) * 1024 + col0 + j * 16] = f2bf(acc[i][j][r] * osc);
}

// ---------- kernel 3: per-group V transpose (round-1 proven) ----------
__global__ __launch_bounds__(256) void vtrans_kernel(
    const unsigned short* __restrict__ V, unsigned short* __restrict__ Vt) {
  __shared__ unsigned short T[128 * 136];
  const int g  = blockIdx.x >> 4;
  const int kt = blockIdx.x & 15;
  const unsigned short* Vg = V + (size_t)g * 262144 + (size_t)kt * 128 * 128;
  unsigned short* Vtg = Vt + (size_t)g * 262144 + kt * 128;
  const int t = threadIdx.x;
#pragma unroll
  for (int it = 0; it < 8; it++) {
    int seg = t + it * 256;
    int k  = seg >> 4;
    int c8 = (seg & 15) << 3;
    uint4 a = *(const uint4*)(Vg + k * 128 + c8);
    unsigned short* Tp = &T[c8 * 136 + k];
    Tp[0 * 136] = (unsigned short)(a.x & 0xffff);
    Tp[1 * 136] = (unsigned short)(a.x >> 16);
    Tp[2 * 136] = (unsigned short)(a.y & 0xffff);
    Tp[3 * 136] = (unsigned short)(a.y >> 16);
    Tp[4 * 136] = (unsigned short)(a.z & 0xffff);
    Tp[5 * 136] = (unsigned short)(a.z >> 16);
    Tp[6 * 136] = (unsigned short)(a.w & 0xffff);
    Tp[7 * 136] = (unsigned short)(a.w >> 16);
  }
  __syncthreads();
#pragma unroll
  for (int it = 0; it < 8; it++) {
    int seg = t + it * 256;
    int c  = seg >> 4;
    int k8 = (seg & 15) << 3;
    uint4 o = *(const uint4*)&T[c * 136 + k8];
    *(uint4*)(Vtg + (size_t)c * 2048 + k8) = o;
  }
}

// ---------- kernel 4 v4: flash attention, VALU-reduced ----------
// v4 changes vs v3 (schedule/layout identical): Q pre-scaled upstream (no
// per-score mul); native v_exp_f32 via builtin; P pack via v_cvt_pk_bf16_f32;
// all swizzled LDS offsets precomputed in registers; kt-loop unrolled x2 so
// buffer bases are compile-time; strength-reduced prefetch pointers.
#define ATTN_TILE(KSH, VSH, KST, VST, PREF)                                    \
  {                                                                            \
    if (PREF) {                                                                \
      gld_lds16(kp + kS0, (KST) + kD0);                                        \
      gld_lds16(kp + kS1, (KST) + kD1);                                        \
      gld_lds16(vp + vS0, (VST) + vD0);                                        \
      gld_lds16(vp + vS1, (VST) + vD1);                                        \
      kp += 8192; vp += 64;                                                    \
    }                                                                          \
    _Pragma("unroll")                                                          \
    for (int mt = 0; mt < 4; mt++) {                                           \
      bf16x8 kf[4];                                                            \
      _Pragma("unroll")                                                        \
      for (int kc = 0; kc < 4; kc++)                                           \
        kf[kc] = *(const bf16x8*)((KSH) + kfO[mt][kc]);                        \
      f32x4 s = (f32x4){0.f, 0.f, 0.f, 0.f};                                   \
      _Pragma("unroll")                                                        \
      for (int kc = 0; kc < 4; kc++)                                           \
        s = __builtin_amdgcn_mfma_f32_16x16x32_bf16(kf[kc], qf[kc], s, 0, 0, 0);\
      float e0 = __builtin_amdgcn_exp2f(fminf(s[0], 30.f));                    \
      float e1 = __builtin_amdgcn_exp2f(fminf(s[1], 30.f));                    \
      float e2 = __builtin_amdgcn_exp2f(fminf(s[2], 30.f));                    \
      float e3 = __builtin_amdgcn_exp2f(fminf(s[3], 30.f));                    \
      lp += (e0 + e1) + (e2 + e3);                                             \
      unsigned u01, u23;                                                       \
      asm("v_cvt_pk_bf16_f32 %0, %1, %2" : "=v"(u01) : "v"(e0), "v"(e1));      \
      asm("v_cvt_pk_bf16_f32 %0, %1, %2" : "=v"(u23) : "v"(e2), "v"(e3));      \
      uint2 u2; u2.x = u01; u2.y = u23;                                        \
      *(uint2*)(Psh + pWr[mt]) = u2;                                           \
    }                                                                          \
    {                                                                          \
      bf16x8 pf0 = *(const bf16x8*)(Psh + pRd0);                               \
      bf16x8 pf1 = *(const bf16x8*)(Psh + pRd1);                               \
      _Pragma("unroll")                                                        \
      for (int cb = 0; cb < 8; cb++) {                                         \
        O[cb] = __builtin_amdgcn_mfma_f32_16x16x32_bf16(                       \
            pf0, *(const bf16x8*)((VSH) + vfO[cb][0]), O[cb], 0, 0, 0);        \
        O[cb] = __builtin_amdgcn_mfma_f32_16x16x32_bf16(                       \
            pf1, *(const bf16x8*)((VSH) + vfO[cb][1]), O[cb], 0, 0, 0);        \
      }                                                                        \
    }                                                                          \
    __syncthreads();                                                           \
  }

__global__ __launch_bounds__(512, 4) void attn_kernel(
    const unsigned short* __restrict__ Q,
    const unsigned short* __restrict__ K,
    const unsigned short* __restrict__ Vt,   // bf16 [64][128 chunk][2048 key]
    unsigned short* __restrict__ ctx) {
  // Kbuf[b] = smem + b*16384        [64 key][256B], chunk c at p=(c&8)|((c^r)&7)
  // Vbuf[b] = smem + 32768 + b*16384 [128 chunk][128B], chunk c at p=c^(r&7)
  // Psh     = smem + 65536          [128 qrow][128B], chunk c at p=c^(r&7)
  __shared__ unsigned char smem[81920];
  unsigned char* Psh = smem + 65536;

  const int g  = blockIdx.x >> 4;
  const int qt = blockIdx.x & 15;
  const unsigned short* Qg = Q + (size_t)g * 262144 + (size_t)qt * 16384;
  const unsigned short* Kg = K + (size_t)g * 262144;
  const unsigned short* Vg = Vt + (size_t)g * 262144;   // [128][2048]

  const int t    = threadIdx.x;
  const int lane = t & 63;
  const int wv   = t >> 6;          // 0..7, wave owns qrows [wv*16, wv*16+16)
  const int fr   = lane & 15;
  const int quad = lane >> 4;
  const int qrow = wv * 16 + fr;

  // ---- precomputed swizzled LDS byte offsets (loop-invariant, registers) ----
  int kfO[4][4];
#pragma unroll
  for (int mt = 0; mt < 4; mt++)
#pragma unroll
    for (int kc = 0; kc < 4; kc++) {
      int row = mt * 16 + fr;
      int c = kc * 4 + quad;
      int p = (c & 8) | ((c ^ (row & 7)) & 7);
      kfO[mt][kc] = row * 256 + p * 16;
    }
  int vfO[8][2];
#pragma unroll
  for (int cb = 0; cb < 8; cb++)
#pragma unroll
    for (int k2 = 0; k2 < 2; k2++) {
      int crow = cb * 16 + fr;
      int c = k2 * 4 + quad;
      int p = c ^ (crow & 7);
      vfO[cb][k2] = crow * 128 + p * 16;
    }
  int pWr[4];
#pragma unroll
  for (int mt = 0; mt < 4; mt++) {
    int cP = mt * 2 + (quad >> 1);
    int pP = cP ^ (qrow & 7);
    pWr[mt] = qrow * 128 + pP * 16 + (quad & 1) * 8;
  }
  int pRd0, pRd1;
  {
    int c0 = quad,     p0 = c0 ^ (qrow & 7);
    int c1 = 4 + quad, p1 = c1 ^ (qrow & 7);
    pRd0 = qrow * 128 + p0 * 16;
    pRd1 = qrow * 128 + p1 * 16;
  }
  // staging source/dest offsets (K: seg=t,t+512 ; V: same segs, V geometry)
  int kS0, kS1, kD0, kD1, vS0, vS1, vD0, vD1;
  {
    int seg0 = t, seg1 = t + 512;
    int r0 = seg0 >> 4, p0 = seg0 & 15, c0 = (p0 & 8) | ((p0 ^ r0) & 7);
    int r1 = seg1 >> 4, p1 = seg1 & 15, c1 = (p1 & 8) | ((p1 ^ r1) & 7);
    kS0 = r0 * 128 + c0 * 8;  kD0 = seg0 * 16;
    kS1 = r1 * 128 + c1 * 8;  kD1 = seg1 * 16;
    int vr0 = seg0 >> 3, vp0 = seg0 & 7, vc0 = vp0 ^ (vr0 & 7);
    int vr1 = seg1 >> 3, vp1 = seg1 & 7, vc1 = vp1 ^ (vr1 & 7);
    vS0 = vr0 * 2048 + vc0 * 8;  vD0 = seg0 * 16;
    vS1 = vr1 * 2048 + vc1 * 8;  vD1 = seg1 * 16;
  }

  // stage Q [128 rows x 256B] swizzled into smem[0..32768)
#pragma unroll
  for (int it = 0; it < 4; it++) {
    int seg = t + it * 512;
    int r = seg >> 4, p = seg & 15;
    int c = (p & 8) | ((p ^ r) & 7);
    gld_lds16(Qg + r * 128 + c * 8, smem + seg * 16);
  }
  __syncthreads();
  bf16x8 qf[4];   // B-frag: Q[qrow][k = kc*32+quad*8+j]  (Q pre-scaled by SCLOG)
#pragma unroll
  for (int kc = 0; kc < 4; kc++) {
    int c = kc * 4 + quad;
    int p = (c & 8) | ((c ^ (qrow & 7)) & 7);
    qf[kc] = *(const bf16x8*)(smem + qrow * 256 + p * 16);
  }
  __syncthreads();   // all waves done reading Q region (Kbufs overlay it)

  // prologue: stage tile 0 into buffer 0
  gld_lds16(Kg + kS0, smem + kD0);
  gld_lds16(Kg + kS1, smem + kD1);
  gld_lds16(Vg + vS0, smem + 32768 + vD0);
  gld_lds16(Vg + vS1, smem + 32768 + vD1);
  __syncthreads();

  const unsigned short* kp = Kg + 8192;   // tile 1 (64 keys * 128 elems)
  const unsigned short* vp = Vg + 64;     // tile 1 (64-key column step)

  f32x4 O[8];   // D[qrow][chunk cb]
#pragma unroll
  for (int cb = 0; cb < 8; cb++) O[cb] = (f32x4){0.f, 0.f, 0.f, 0.f};
  float lp = 0.f;

  unsigned char* B0K = smem;
  unsigned char* B1K = smem + 16384;
  unsigned char* B0V = smem + 32768;
  unsigned char* B1V = smem + 49152;

#pragma unroll 1
  for (int kt2 = 0; kt2 < 16; kt2++) {
    ATTN_TILE(B0K, B0V, B1K, B1V, 1);              // tile 2*kt2, prefetch +1
    ATTN_TILE(B1K, B1V, B0K, B0V, (kt2 < 15));     // tile 2*kt2+1, prefetch +2
  }

  // row-sum across quads, then normalize + write ctx (linv overlaid on Psh)
  float* linv_arr = (float*)(smem + 65536);
  {
    float v = lp;
    v += __shfl_xor(v, 16);
    v += __shfl_xor(v, 32);
    if (quad == 0) linv_arr[wv * 16 + fr] = 1.f / v;
  }
  unsigned short* Cg = ctx + (size_t)g * 262144 + (size_t)qt * 16384;
  float li[4];
#pragma unroll
  for (int r = 0; r < 4; r++) li[r] = linv_arr[wv * 16 + quad * 4 + r];
#pragma unroll
  for (int cb = 0; cb < 8; cb++)
#pragma unroll
    for (int r = 0; r < 4; r++) {
      int orow = wv * 16 + quad * 4 + r;
      Cg[(size_t)orow * 128 + cb * 16 + fr] = f2bf(O[cb][r] * li[r]);
    }
}

// ---------- kernel 5: output projection + bias + residual ----------
__global__ __launch_bounds__(256) void gemm_proj_kernel(
    const unsigned short* __restrict__ A,
    const unsigned short* __restrict__ W,
    const float* __restrict__ bp,
    const float* __restrict__ qres,
    float* __restrict__ out) {
  __shared__ unsigned short Alds[128 * 32];
  __shared__ unsigned short Blds[128 * 32];
  const int t   = threadIdx.x;
  const int bid = blockIdx.x;
  const int tn  = bid % 8;
  const int tm  = bid / 8;
  const unsigned short* Bptr = W + (size_t)tn * 128 * 1024;

  const int lane = t & 63;
  const int wv   = t >> 6;
  const int wm   = (wv >> 1) * 64;
  const int wn   = (wv & 1) * 64;
  const int fr   = lane & 15;
  const int kq   = (lane >> 4) * 8;

  f32x4 acc[4][4];
#pragma unroll
  for (int i = 0; i < 4; i++)
#pragma unroll
    for (int j = 0; j < 4; j++) acc[i][j] = (f32x4){0.f, 0.f, 0.f, 0.f};

  const int sr = t >> 2;
  const int sc = (t & 3) << 3;
  const unsigned short* gA = A + (size_t)(tm * 128 + sr) * 1024 + sc;
  const unsigned short* gB = Bptr + (size_t)sr * 1024 + sc;
  unsigned short* lA = Alds + t * 8;
  unsigned short* lB = Blds + t * 8;

  for (int k0 = 0; k0 < 1024; k0 += 32) {
    gld_lds16(gA, lA);
    gld_lds16(gA + 64 * 1024, lA + 64 * 32);
    gld_lds16(gB, lB);
    gld_lds16(gB + 64 * 1024, lB + 64 * 32);
    gA += 32; gB += 32;
    __syncthreads();
    bf16x8 af[4], bfr[4];
#pragma unroll
    for (int i = 0; i < 4; i++) {
      af[i]  = *(const bf16x8*)&Alds[(wm + i * 16 + fr) * 32 + kq];
      bfr[i] = *(const bf16x8*)&Blds[(wn + i * 16 + fr) * 32 + kq];
    }
#pragma unroll
    for (int i = 0; i < 4; i++)
#pragma unroll
      for (int j = 0; j < 4; j++)
        acc[i][j] = __builtin_amdgcn_mfma_f32_16x16x32_bf16(af[i], bfr[j], acc[i][j], 0, 0, 0);
    __syncthreads();
  }

  const int quad = lane >> 4;
  const int cc   = lane & 15;
#pragma unroll
  for (int i = 0; i < 4; i++)
#pragma unroll
    for (int j = 0; j < 4; j++)
#pragma unroll
      for (int r = 0; r < 4; r++) {
        int row = tm * 128 + wm + i * 16 + quad * 4 + r;
        int col = tn * 128 + wn + j * 16 + cc;
        out[(size_t)row * 1024 + col] =
            acc[i][j][r] + bp[col] + qres[(size_t)row * 1024 + col];
      }
}

// ---------- kernel 6: in-place LayerNorm ----------
__global__ __launch_bounds__(256) void ln_kernel(float* __restrict__ out,
                                                 const float* __restrict__ gamma,
                                                 const float* __restrict__ beta) {
  __shared__ float red[8];
  const int row = blockIdx.x;
  float* p = out + (size_t)row * 1024;
  const int t = threadIdx.x;
  float4 v = ((const float4*)p)[t];
  float s  = v.x + v.y + v.z + v.w;
  float s2 = v.x * v.x + v.y * v.y + v.z * v.z + v.w * v.w;
#pragma unroll
  for (int off = 1; off < 64; off <<= 1) {
    s  += __shfl_xor(s, off);
    s2 += __shfl_xor(s2, off);
  }
  const int wv = t >> 6;
  if ((t & 63) == 0) { red[wv] = s; red[4 + wv] = s2; }
  __syncthreads();
  float S  = red[0] + red[1] + red[2] + red[3];
  float S2 = red[4] + red[5] + red[6] + red[7];
  float mu  = S * (1.f / 1024.f);
  float var = S2 * (1.f / 1024.f) - mu * mu;
  float rstd = rsqrtf(var + 1e-5f);
  float4 gm = ((const float4*)gamma)[t];
  float4 bt = ((const float4*)beta)[t];
  v.x = (v.x - mu) * rstd * gm.x + bt.x;
  v.y = (v.y - mu) * rstd * gm.y + bt.y;
  v.z = (v.z - mu) * rstd * gm.z + bt.z;
  v.w = (v.w - mu) * rstd * gm.w + bt.w;
  ((float4*)p)[t] = v;
}

// ---------- launch ----------
extern "C" void kernel_launch(void* const* d_in, const int* in_sizes, int n_in,
                              void* d_out, int out_size, void* d_ws, size_t ws_size,
                              hipStream_t stream) {
  const float* query = (const float*)d_in[0];
  const float* keys  = (const float*)d_in[1];
  const float* Wq    = (const float*)d_in[2];
  const float* Wk    = (const float*)d_in[3];
  const float* Wv    = (const float*)d_in[4];
  const float* Wp    = (const float*)d_in[5];
  const float* bp    = (const float*)d_in[6];
  const float* gamma = (const float*)d_in[7];
  const float* beta  = (const float*)d_in[8];
  float* out = (float*)d_out;

  unsigned short* ws   = (unsigned short*)d_ws;
  unsigned short* qb   = ws;                 // 16777216
  unsigned short* kb   = ws + 16777216;      // 16777216
  unsigned short* Wqkv = ws + 33554432;      // 3145728
  unsigned short* Wpb  = ws + 36700160;      // 1048576
  unsigned short* Qb   = ws + 37748736;      // 16777216
  unsigned short* Kb   = ws + 54525952;      // 16777216
  unsigned short* Vb   = ws + 71303168;      // 16777216
  unsigned short* Vtb  = kb;                 // reuse (kb dead after QKV GEMM)
  unsigned short* ctx  = qb;                 // reuse (qb dead after QKV GEMM)

  convert_kernel<<<36864, 256, 0, stream>>>(query, keys, Wq, Wk, Wv, Wp, qb, kb, Wqkv, Wpb);
  gemm_qkv8_kernel<<<768, 512, 0, stream>>>(qb, kb, Wqkv, Qb, Kb, Vb);
  vtrans_kernel<<<1024, 256, 0, stream>>>(Vb, Vtb);
  attn_kernel<<<1024, 512, 0, stream>>>(Qb, Kb, Vtb, ctx);
  gemm_proj_kernel<<<1024, 256, 0, stream>>>(ctx, Wpb, bp, query, out);
  ln_kernel<<<16384, 256, 0, stream>>>(out, gamma, beta);
}